// Round 4
// baseline (418.917 us; speedup 1.0000x reference)
//
#include <hip/hip_runtime.h>

typedef unsigned short ushort_t;
typedef short bf16x8 __attribute__((ext_vector_type(8)));
typedef float f32x4 __attribute__((ext_vector_type(4)));

#define D_MODEL 2048
#define T_SEQ 2048
#define NB 2
#define NH 16
#define HD 128
#define M_ROWS 4096

__device__ __forceinline__ float b2f(unsigned short u) {
    return __uint_as_float(((unsigned)u) << 16);
}
__device__ __forceinline__ unsigned short f2b(float f) {
    unsigned u = __float_as_uint(f);
    u += 0x7fffu + ((u >> 16) & 1u);
    return (unsigned short)(u >> 16);
}

// async global->LDS, 16B per lane. lds base must be wave-uniform.
__device__ __forceinline__ void g2l16(const ushort_t* g, ushort_t* l) {
    __builtin_amdgcn_global_load_lds(
        (const __attribute__((address_space(1))) unsigned int*)g,
        (__attribute__((address_space(3))) unsigned int*)l, 16, 0, 0);
}

// ---------------------------------------------------------------------------
// Input dtype probe (1 = fp32 inputs).
// ---------------------------------------------------------------------------
__global__ void detect_dtype(const ushort_t* __restrict__ x, int* __restrict__ flag) {
    __shared__ int cnt;
    if (threadIdx.x == 0) cnt = 0;
    __syncthreads();
    int c = 0;
    for (int i = threadIdx.x; i < 8192; i += 256) {
        int e = (x[i] >> 7) & 0xFF;
        if (e >= 0xC8) ++c;
    }
    atomicAdd(&cnt, c);
    __syncthreads();
    if (threadIdx.x == 0) *flag = (cnt > 16) ? 1 : 0;
}

// ---------------------------------------------------------------------------
// One fused conversion pass for x + 4 weight matrices (dsts are contiguous
// in the workspace: [x | Wq | Wk | Wv | Wo]). Saves 4 launch overheads.
// ---------------------------------------------------------------------------
__global__ void convert_all(const void* __restrict__ s0, const void* __restrict__ s1,
                            const void* __restrict__ s2, const void* __restrict__ s3,
                            const void* __restrict__ s4, ushort_t* __restrict__ dst,
                            const int* __restrict__ flag) {
    const size_t TENc = (size_t)M_ROWS * D_MODEL;   // 2^23
    const size_t WELc = (size_t)D_MODEL * D_MODEL;  // 2^22
    size_t i = ((size_t)blockIdx.x * 256 + threadIdx.x) * 8;
    const void* src;
    size_t off;
    if (i < TENc) {
        src = s0; off = i;
    } else {
        size_t j = i - TENc;
        int wsel = (int)(j >> 22);
        src = (wsel == 0) ? s1 : (wsel == 1) ? s2 : (wsel == 2) ? s3 : s4;
        off = j & (WELc - 1);
    }
    if (*flag) {
        const float* s = (const float*)src + off;
        union { ushort_t u[8]; float4 f; } pk;
        #pragma unroll
        for (int j2 = 0; j2 < 8; ++j2) pk.u[j2] = f2b(s[j2]);
        *(float4*)(dst + i) = pk.f;
    } else {
        *(float4*)(dst + i) = *(const float4*)((const ushort_t*)src + off);
    }
}

// ---------------------------------------------------------------------------
// RoPE cos/sin table: tab[t*128 + i] = cos(t*invf(i)), tab[t*128+64+i] = sin.
// ---------------------------------------------------------------------------
__global__ void rope_table(float* __restrict__ tab) {
    int tid = blockIdx.x * 256 + threadIdx.x;   // t*64 + i
    int i = tid & 63, t = tid >> 6;
    float ang = (float)t * exp2f(-(float)i * 0.20762050593046015f);
    tab[t * 128 + i]      = cosf(ang);
    tab[t * 128 + 64 + i] = sinf(ang);
}

// ---------------------------------------------------------------------------
// NT GEMM, 128x128 tile, 2-phase double-buffered K-loop (R3) + XCD swizzle.
// R1 post-mortem kept: one weight matrix per launch — fusing Q/K/V blew the
// per-XCD L2 working set and regressed badly.
// mode 0: plain bf16 store (or fp32 if outf && *flag)
// mode 1: fused RoPE (table) then bf16 store       (Q/K projections)
// mode 2: store transposed to Vt (B,H,hd,T) layout (V projection)
// ---------------------------------------------------------------------------
#define SBUF (2 * 128 * 64)   // elements per phase buffer (As|Ws)

__global__ __launch_bounds__(256) void gemm_nt(const ushort_t* __restrict__ A,
                                               const ushort_t* __restrict__ W,
                                               ushort_t* __restrict__ C,
                                               float* __restrict__ outf,
                                               const int* __restrict__ flag,
                                               const float* __restrict__ rtab,
                                               int mode, int Kdim, int Ndim) {
    __shared__ ushort_t smem[2 * SBUF];   // 64 KB: two (As|Ws) buffers
    const int tid  = threadIdx.x;
    const int lane = tid & 63;
    const int w    = tid >> 6;
    const int wr   = (w >> 1) * 64, wc = (w & 1) * 64;
    const int quad = lane >> 4, l16 = lane & 15;

    // XCD-aware bijective swizzle (all grids here have nwg % 8 == 0).
    const int nwg = gridDim.x * gridDim.y;
    const int wg  = blockIdx.y * gridDim.x + blockIdx.x;
    const int swz = (wg & 7) * (nwg >> 3) + (wg >> 3);
    const long bm = (long)(swz / gridDim.x) * 128;
    const long bn = (long)(swz % gridDim.x) * 128;

    f32x4 acc[4][4];
    for (int i = 0; i < 4; ++i)
        for (int j = 0; j < 4; ++j) acc[i][j] = {0.f, 0.f, 0.f, 0.f};

    const int ck0 = w * 256 + lane;
    const int sw = l16 & 7;

    auto stage = [&](int kb, int buf) {
        ushort_t* As = smem + buf * SBUF;
        ushort_t* Ws = As + 128 * 64;
        #pragma unroll
        for (int i = 0; i < 4; ++i) {
            int ck = ck0 + i * 64;
            int r = ck >> 3, g8 = (ck & 7) ^ (r & 7);
            g2l16(A + (bm + r) * Kdim + kb + g8 * 8, As + (size_t)(w * 256 + i * 64) * 8);
            g2l16(W + (bn + r) * Kdim + kb + g8 * 8, Ws + (size_t)(w * 256 + i * 64) * 8);
        }
    };

    stage(0, 0);
    __syncthreads();
    int cur = 0;
    for (int kb = 0; kb < Kdim; kb += 64) {
        if (kb + 64 < Kdim) stage(kb + 64, cur ^ 1);
        const ushort_t* As = smem + cur * SBUF;
        const ushort_t* Ws = As + 128 * 64;
        #pragma unroll
        for (int kk = 0; kk < 64; kk += 32) {
            const int gb = kk >> 3;
            bf16x8 af[4], bf[4];
            #pragma unroll
            for (int i = 0; i < 4; ++i)
                af[i] = *(const bf16x8*)(As + (wr + i * 16 + l16) * 64 + ((gb + quad) ^ sw) * 8);
            #pragma unroll
            for (int j = 0; j < 4; ++j)
                bf[j] = *(const bf16x8*)(Ws + (wc + j * 16 + l16) * 64 + ((gb + quad) ^ sw) * 8);
            #pragma unroll
            for (int i = 0; i < 4; ++i)
                #pragma unroll
                for (int j = 0; j < 4; ++j)
                    acc[i][j] = __builtin_amdgcn_mfma_f32_16x16x32_bf16(af[i], bf[j], acc[i][j], 0, 0, 0);
        }
        __syncthreads();
        cur ^= 1;
    }

    if (mode == 2) {
        // ---- Vt epilogue: scatter transposed (d-major) into LDS, store along t.
        #pragma unroll
        for (int i = 0; i < 4; ++i)
            #pragma unroll
            for (int j = 0; j < 4; ++j)
                #pragma unroll
                for (int r = 0; r < 4; ++r) {
                    int row = wr + i * 16 + quad * 4 + r;    // t within tile
                    int col = wc + j * 16 + l16;             // d within head
                    smem[col * 128 + ((((row >> 3) ^ (col & 7)) << 3) | (row & 7))] =
                        f2b(acc[i][j][r]);
                }
        __syncthreads();
        const int b = (int)(bm >> 11), t0 = (int)(bm & 2047), h = (int)(bn >> 7);
        const size_t obase = ((size_t)(b * NH + h) * HD) * T_SEQ;
        #pragma unroll
        for (int it = 0; it < 8; ++it) {
            int dd = it * 16 + (tid >> 4);
            int tch = tid & 15;
            bf16x8 v = *(const bf16x8*)(smem + dd * 128 + ((tch ^ (dd & 7)) << 3));
            *(bf16x8*)(C + obase + (size_t)dd * T_SEQ + t0 + tch * 8) = v;
        }
        return;
    }

    const int as_f32 = (outf != nullptr) && (*flag != 0);
    if (!as_f32) {
        // standard scatter: chunk ^= row&7
        #pragma unroll
        for (int i = 0; i < 4; ++i)
            #pragma unroll
            for (int j = 0; j < 4; ++j)
                #pragma unroll
                for (int r = 0; r < 4; ++r) {
                    int row = wr + i * 16 + quad * 4 + r;
                    int col = wc + j * 16 + l16;
                    int ch = col >> 3, off = col & 7;
                    smem[row * 128 + (((ch ^ (row & 7)) << 3) | off)] = f2b(acc[i][j][r]);
                }
        __syncthreads();
        if (mode == 1) {
            // fused RoPE: col pairs (i, i+64) are chunks (ch, ch^8) of same row.
            #pragma unroll
            for (int it = 0; it < 8; ++it) {
                int row = it * 16 + (tid >> 4);
                int ch  = tid & 15;
                int t = (int)((bm + row) & 2047);
                bf16x8 v = *(const bf16x8*)(smem + row * 128 + ((ch ^ (row & 7)) << 3));
                bf16x8 p = *(const bf16x8*)(smem + row * 128 + (((ch ^ 8) ^ (row & 7)) << 3));
                const float* cr = rtab + t * 128 + (ch & 7) * 8;
                float sgn = (ch < 8) ? -1.f : 1.f;
                union { ushort_t u[8]; float4 f[1]; } o;
                #pragma unroll
                for (int j = 0; j < 8; ++j) {
                    float cv = cr[j], sv = cr[64 + j];
                    o.u[j] = f2b(b2f(((const ushort_t*)&v)[j]) * cv +
                                 sgn * b2f(((const ushort_t*)&p)[j]) * sv);
                }
                *(bf16x8*)(C + (bm + row) * Ndim + bn + ch * 8) = *(const bf16x8*)o.u;
            }
        } else {
            #pragma unroll
            for (int it = 0; it < 8; ++it) {
                int row = it * 16 + (tid >> 4);
                int ch  = tid & 15;
                bf16x8 v = *(const bf16x8*)(smem + row * 128 + ((ch ^ (row & 7)) << 3));
                *(bf16x8*)(C + (bm + row) * Ndim + bn + ch * 8) = v;
            }
        }
    } else {
        // fp32 epilogue: two 64-row halves through 32KB LDS
        float* Fs = (float*)smem;
        #pragma unroll
        for (int half = 0; half < 2; ++half) {
            __syncthreads();
            if ((w >> 1) == half) {
                #pragma unroll
                for (int i = 0; i < 4; ++i)
                    #pragma unroll
                    for (int j = 0; j < 4; ++j)
                        #pragma unroll
                        for (int r = 0; r < 4; ++r) {
                            int lr = i * 16 + quad * 4 + r;
                            int col = wc + j * 16 + l16;
                            int ch = col >> 2, off = col & 3;
                            Fs[lr * 128 + (((ch ^ (lr & 7)) << 2) | off)] = acc[i][j][r];
                        }
            }
            __syncthreads();
            #pragma unroll
            for (int it = 0; it < 8; ++it) {
                int lr = it * 8 + (tid >> 5);
                int ch = tid & 31;
                float4 v = *(const float4*)(Fs + lr * 128 + ((ch ^ (lr & 7)) << 2));
                *(float4*)(outf + (bm + half * 64 + lr) * Ndim + bn + ch * 4) = v;
            }
        }
    }
}

// ---------------------------------------------------------------------------
// Causal flash attention, fixed-M softmax (exact: shift-invariant, bounded
// scores keep exp2 args in range).
//
// R4: complementary q-tile PAIRING. Block p handles q-tiles qhi=31-p and
// qlo=p of one (b,h), iterating kv tiles 0..qhi and computing BOTH tiles
// against the SAME staged K/V tile while kvb<=qlo:
//   - per-block compute-units = 2*(qlo+1) + (qhi-qlo) = 33, CONSTANT ->
//     perfect load balance (was 1:32 spread -> ~25-35% machine idle tail)
//   - each LDS K/V fragment read feeds two MFMAs in the overlap region
//     (32 MFMAs between barriers instead of 16)
//   - K/V staged once per pair instead of once per tile
// Grid: 512 blocks = 2/CU, all co-resident. Barrier structure per iteration
// unchanged from R2 (2x __syncthreads, same hazard proof).
// LDS: Ks 16K + Vs 16K + Ps 2x8K = 48K.
// ---------------------------------------------------------------------------
#define NQT (T_SEQ / 64)
#define C2SM 0.1275174452f   // 128^-0.5 * log2(e)
#define MFIX 96.0f

__global__ __launch_bounds__(256, 2) void attn_kernel(const ushort_t* __restrict__ Q,
                                                      const ushort_t* __restrict__ K,
                                                      const ushort_t* __restrict__ Vt,
                                                      ushort_t* __restrict__ O) {
    __shared__ ushort_t Ks[64 * 128];
    __shared__ ushort_t Vs[128 * 64];
    __shared__ ushort_t Ps0[4 * 16 * 64];
    __shared__ ushort_t Ps1[4 * 16 * 64];

    const int tid = threadIdx.x;
    const int lane = tid & 63, w = tid >> 6;
    const int quad = lane >> 4, l16 = lane & 15;
    const int bx = blockIdx.x;
    const int pair = bx >> 5;                 // 0..15
    const int bh = bx & 31;
    const int h = bh & 15, b = bh >> 4;
    const int qhi = (NQT - 1) - pair;         // 16..31
    const int qlo = pair;                     // 0..15

    const size_t qkbase = ((size_t)(b * T_SEQ)) * D_MODEL + h * HD;
    const size_t vtbase = ((size_t)((b * NH + h) * HD)) * T_SEQ;
    const int ck0 = w * 256 + lane;
    ushort_t* Pw0 = Ps0 + w * 1024;
    ushort_t* Pw1 = Ps1 + w * 1024;

    auto stage_K = [&](int kvb) {
        #pragma unroll
        for (int i = 0; i < 4; ++i) {
            int ck = ck0 + i * 64;
            int r = ck >> 4, g = (ck & 15) ^ (r & 15);
            g2l16(K + qkbase + (size_t)(kvb * 64 + r) * D_MODEL + g * 8,
                  (ushort_t*)Ks + (size_t)(w * 256 + i * 64) * 8);
        }
    };
    auto stage_V = [&](int kvb) {
        #pragma unroll
        for (int i = 0; i < 4; ++i) {
            int ck = ck0 + i * 64;
            int r = ck >> 3, g = (ck & 7) ^ (r & 7);
            g2l16(Vt + vtbase + (size_t)r * T_SEQ + kvb * 64 + g * 8,
                  (ushort_t*)Vs + (size_t)(w * 256 + i * 64) * 8);
        }
    };

    bf16x8 qfh[4], qfl[4];
    {
        const ushort_t* qrh = Q + qkbase + (size_t)(qhi * 64 + w * 16 + l16) * D_MODEL;
        const ushort_t* qrl = Q + qkbase + (size_t)(qlo * 64 + w * 16 + l16) * D_MODEL;
        #pragma unroll
        for (int ks = 0; ks < 4; ++ks) {
            qfh[ks] = *(const bf16x8*)(qrh + ks * 32 + quad * 8);
            qfl[ks] = *(const bf16x8*)(qrl + ks * 32 + quad * 8);
        }
    }

    float l_h[4] = {0.f, 0.f, 0.f, 0.f};
    float l_l[4] = {0.f, 0.f, 0.f, 0.f};
    f32x4 accOh[8], accOl[8];
    for (int i = 0; i < 8; ++i) { accOh[i] = {0.f, 0.f, 0.f, 0.f}; accOl[i] = {0.f, 0.f, 0.f, 0.f}; }

    stage_K(0);                              // prologue

    for (int kvb = 0; kvb <= qhi; ++kvb) {
        const bool lo_act = (kvb <= qlo);
        __syncthreads();                     // K(kvb) landed; Vs free
        stage_V(kvb);                        // in flight during QK^T+softmax

        f32x4 aSh[4], aSl[4];
        for (int i = 0; i < 4; ++i) { aSh[i] = {0.f, 0.f, 0.f, 0.f}; aSl[i] = {0.f, 0.f, 0.f, 0.f}; }
        __builtin_amdgcn_s_setprio(1);
        if (lo_act) {
            #pragma unroll
            for (int ks = 0; ks < 4; ++ks) {
                #pragma unroll
                for (int ct = 0; ct < 4; ++ct) {
                    bf16x8 bb = *(const bf16x8*)(Ks + (ct * 16 + l16) * 128 +
                                                 (((ks * 4 + quad) ^ l16) * 8));
                    aSh[ct] = __builtin_amdgcn_mfma_f32_16x16x32_bf16(qfh[ks], bb, aSh[ct], 0, 0, 0);
                    aSl[ct] = __builtin_amdgcn_mfma_f32_16x16x32_bf16(qfl[ks], bb, aSl[ct], 0, 0, 0);
                }
            }
        } else {
            #pragma unroll
            for (int ks = 0; ks < 4; ++ks) {
                #pragma unroll
                for (int ct = 0; ct < 4; ++ct) {
                    bf16x8 bb = *(const bf16x8*)(Ks + (ct * 16 + l16) * 128 +
                                                 (((ks * 4 + quad) ^ l16) * 8));
                    aSh[ct] = __builtin_amdgcn_mfma_f32_16x16x32_bf16(qfh[ks], bb, aSh[ct], 0, 0, 0);
                }
            }
        }
        __builtin_amdgcn_s_setprio(0);

        // causal masks (diagonal tiles)
        if (kvb == qhi) {
            int qloc = w * 16 + quad * 4;
            for (int ct = 0; ct < 4; ++ct) {
                int key = ct * 16 + l16;
                for (int r = 0; r < 4; ++r)
                    if (key > qloc + r) aSh[ct][r] = -1e30f;
            }
        }
        if (lo_act && kvb == qlo) {
            int qloc = w * 16 + quad * 4;
            for (int ct = 0; ct < 4; ++ct) {
                int key = ct * 16 + l16;
                for (int r = 0; r < 4; ++r)
                    if (key > qloc + r) aSl[ct][r] = -1e30f;
            }
        }

        // softmax numerators -> P buffers (per-wave, no barrier needed)
        #pragma unroll
        for (int ct = 0; ct < 4; ++ct) {
            #pragma unroll
            for (int r = 0; r < 4; ++r) {
                float pv = exp2f((aSh[ct][r] - MFIX) * C2SM);
                l_h[r] += pv;
                int col = ct * 16 + l16;
                int row = quad * 4 + r;
                Pw0[row * 64 + ((((col >> 3) ^ (row & 7)) << 3) | (col & 7))] = f2b(pv);
            }
        }
        if (lo_act) {
            #pragma unroll
            for (int ct = 0; ct < 4; ++ct) {
                #pragma unroll
                for (int r = 0; r < 4; ++r) {
                    float pv = exp2f((aSl[ct][r] - MFIX) * C2SM);
                    l_l[r] += pv;
                    int col = ct * 16 + l16;
                    int row = quad * 4 + r;
                    Pw1[row * 64 + ((((col >> 3) ^ (row & 7)) << 3) | (col & 7))] = f2b(pv);
                }
            }
        }

        __syncthreads();                     // V(kvb) landed; Ks free
        if (kvb < qhi) stage_K(kvb + 1);     // in flight during PV

        __builtin_amdgcn_s_setprio(1);
        if (lo_act) {
            #pragma unroll
            for (int kk2 = 0; kk2 < 2; ++kk2) {
                bf16x8 ah = *(const bf16x8*)(Pw0 + l16 * 64 + (((kk2 * 4 + quad) ^ (l16 & 7)) << 3));
                bf16x8 al = *(const bf16x8*)(Pw1 + l16 * 64 + (((kk2 * 4 + quad) ^ (l16 & 7)) << 3));
                #pragma unroll
                for (int ct = 0; ct < 8; ++ct) {
                    bf16x8 bb = *(const bf16x8*)(Vs + (ct * 16 + l16) * 64 +
                                                 (((kk2 * 4 + quad) ^ (l16 & 7)) * 8));
                    accOh[ct] = __builtin_amdgcn_mfma_f32_16x16x32_bf16(ah, bb, accOh[ct], 0, 0, 0);
                    accOl[ct] = __builtin_amdgcn_mfma_f32_16x16x32_bf16(al, bb, accOl[ct], 0, 0, 0);
                }
            }
        } else {
            #pragma unroll
            for (int kk2 = 0; kk2 < 2; ++kk2) {
                bf16x8 ah = *(const bf16x8*)(Pw0 + l16 * 64 + (((kk2 * 4 + quad) ^ (l16 & 7)) << 3));
                #pragma unroll
                for (int ct = 0; ct < 8; ++ct) {
                    bf16x8 bb = *(const bf16x8*)(Vs + (ct * 16 + l16) * 64 +
                                                 (((kk2 * 4 + quad) ^ (l16 & 7)) * 8));
                    accOh[ct] = __builtin_amdgcn_mfma_f32_16x16x32_bf16(ah, bb, accOh[ct], 0, 0, 0);
                }
            }
        }
        __builtin_amdgcn_s_setprio(0);
    }

    // l reductions across the 16 lanes of each quad group
    #pragma unroll
    for (int r = 0; r < 4; ++r) {
        for (int off = 1; off < 16; off <<= 1) {
            l_h[r] += __shfl_xor(l_h[r], off);
            l_l[r] += __shfl_xor(l_l[r], off);
        }
        l_h[r] = 1.f / l_h[r];
        l_l[r] = 1.f / l_l[r];
    }

    #pragma unroll
    for (int ct = 0; ct < 8; ++ct)
        for (int r = 0; r < 4; ++r) {
            size_t rowh = (size_t)(b * T_SEQ + qhi * 64 + w * 16 + quad * 4 + r);
            O[rowh * D_MODEL + h * HD + ct * 16 + l16] = f2b(accOh[ct][r] * l_h[r]);
            size_t rowl = (size_t)(b * T_SEQ + qlo * 64 + w * 16 + quad * 4 + r);
            O[rowl * D_MODEL + h * HD + ct * 16 + l16] = f2b(accOl[ct][r] * l_l[r]);
        }
}

// ---------------------------------------------------------------------------
extern "C" void kernel_launch(void* const* d_in, const int* in_sizes, int n_in,
                              void* d_out, int out_size, void* d_ws, size_t ws_size,
                              hipStream_t stream) {
    const size_t TEN = (size_t)M_ROWS * D_MODEL;
    const size_t WEL = (size_t)D_MODEL * D_MODEL;

    char* ws = (char*)d_ws;
    int* flag = (int*)ws;
    ushort_t* xb  = (ushort_t*)(ws + 256);
    ushort_t* Wqb = xb  + TEN;
    ushort_t* Wkb = Wqb + WEL;
    ushort_t* Wvb = Wkb + WEL;
    ushort_t* Wob = Wvb + WEL;
    ushort_t* Qb  = Wob + WEL;
    ushort_t* Kb  = Qb + TEN;
    ushort_t* attn = Kb + TEN;        // old Vb slot
    ushort_t* Vt  = attn + TEN;
    float* rtab = (float*)(Vt + TEN); // 2048*128 floats = 1 MB

    detect_dtype<<<1, 256, 0, stream>>>((const ushort_t*)d_in[0], flag);
    rope_table<<<(T_SEQ * 64) / 256, 256, 0, stream>>>(rtab);
    convert_all<<<(int)((TEN + 4 * WEL) / 8 / 256), 256, 0, stream>>>(
        d_in[0], d_in[1], d_in[2], d_in[3], d_in[4], xb, flag);

    dim3 gg(D_MODEL / 128, M_ROWS / 128);
    gemm_nt<<<gg, 256, 0, stream>>>(xb, Wqb, Qb, nullptr, flag, rtab, 1, D_MODEL, D_MODEL);
    gemm_nt<<<gg, 256, 0, stream>>>(xb, Wkb, Kb, nullptr, flag, rtab, 1, D_MODEL, D_MODEL);
    gemm_nt<<<gg, 256, 0, stream>>>(xb, Wvb, Vt, nullptr, flag, rtab, 2, D_MODEL, D_MODEL);
    attn_kernel<<<dim3((NQT / 2) * NB * NH), 256, 0, stream>>>(Qb, Kb, Vt, attn);
    gemm_nt<<<gg, 256, 0, stream>>>(attn, Wob, (ushort_t*)d_out, (float*)d_out, flag,
                                    rtab, 0, D_MODEL, D_MODEL);
}

// Round 5
// 381.233 us; speedup vs baseline: 1.0988x; 1.0988x over previous
//
#include <hip/hip_runtime.h>

typedef unsigned short ushort_t;
typedef short bf16x8 __attribute__((ext_vector_type(8)));
typedef float f32x4 __attribute__((ext_vector_type(4)));

#define D_MODEL 2048
#define T_SEQ 2048
#define NB 2
#define NH 16
#define HD 128
#define M_ROWS 4096

__device__ __forceinline__ float b2f(unsigned short u) {
    return __uint_as_float(((unsigned)u) << 16);
}
__device__ __forceinline__ unsigned short f2b(float f) {
    unsigned u = __float_as_uint(f);
    u += 0x7fffu + ((u >> 16) & 1u);
    return (unsigned short)(u >> 16);
}

// async global->LDS, 16B per lane. lds base must be wave-uniform.
__device__ __forceinline__ void g2l16(const ushort_t* g, ushort_t* l) {
    __builtin_amdgcn_global_load_lds(
        (const __attribute__((address_space(1))) unsigned int*)g,
        (__attribute__((address_space(3))) unsigned int*)l, 16, 0, 0);
}

// ---------------------------------------------------------------------------
// Input dtype probe (1 = fp32 inputs).
// ---------------------------------------------------------------------------
__global__ void detect_dtype(const ushort_t* __restrict__ x, int* __restrict__ flag) {
    __shared__ int cnt;
    if (threadIdx.x == 0) cnt = 0;
    __syncthreads();
    int c = 0;
    for (int i = threadIdx.x; i < 8192; i += 256) {
        int e = (x[i] >> 7) & 0xFF;
        if (e >= 0xC8) ++c;
    }
    atomicAdd(&cnt, c);
    __syncthreads();
    if (threadIdx.x == 0) *flag = (cnt > 16) ? 1 : 0;
}

// ---------------------------------------------------------------------------
// One fused conversion pass for x + 4 weight matrices.
// ---------------------------------------------------------------------------
__global__ void convert_all(const void* __restrict__ s0, const void* __restrict__ s1,
                            const void* __restrict__ s2, const void* __restrict__ s3,
                            const void* __restrict__ s4, ushort_t* __restrict__ dst,
                            const int* __restrict__ flag) {
    const size_t TENc = (size_t)M_ROWS * D_MODEL;   // 2^23
    const size_t WELc = (size_t)D_MODEL * D_MODEL;  // 2^22
    size_t i = ((size_t)blockIdx.x * 256 + threadIdx.x) * 8;
    const void* src;
    size_t off;
    if (i < TENc) {
        src = s0; off = i;
    } else {
        size_t j = i - TENc;
        int wsel = (int)(j >> 22);
        src = (wsel == 0) ? s1 : (wsel == 1) ? s2 : (wsel == 2) ? s3 : s4;
        off = j & (WELc - 1);
    }
    if (*flag) {
        const float* s = (const float*)src + off;
        union { ushort_t u[8]; float4 f; } pk;
        #pragma unroll
        for (int j2 = 0; j2 < 8; ++j2) pk.u[j2] = f2b(s[j2]);
        *(float4*)(dst + i) = pk.f;
    } else {
        *(float4*)(dst + i) = *(const float4*)((const ushort_t*)src + off);
    }
}

// ---------------------------------------------------------------------------
// RoPE cos/sin table: tab[t*128 + i] = cos(t*invf(i)), tab[t*128+64+i] = sin.
// ---------------------------------------------------------------------------
__global__ void rope_table(float* __restrict__ tab) {
    int tid = blockIdx.x * 256 + threadIdx.x;   // t*64 + i
    int i = tid & 63, t = tid >> 6;
    float ang = (float)t * exp2f(-(float)i * 0.20762050593046015f);
    tab[t * 128 + i]      = cosf(ang);
    tab[t * 128 + 64 + i] = sinf(ang);
}

// ---------------------------------------------------------------------------
// R5 GEMM: 256x128 tile, 512 threads (8 waves, 4M x 2N, per-wave 64x64),
// counted-vmcnt double-buffered pipeline (T4): loads for K-tile t+1 stay in
// flight ACROSS the barriers while computing tile t; never drain vmcnt to 0
// in the main loop.
//   prologue: stage(0,b0); stage(1,b1)                 [12 loads in flight]
//   iter t  : s_waitcnt vmcnt(6)   -> S(t) landed, S(t+1)'s 6 still flying
//             s_barrier            -> all waves agree buf[t&1] is ready
//             compute(buf[t&1])    (ds_read + 32 MFMA/wave)
//             s_waitcnt lgkmcnt(0); s_barrier  -> all reads of buf retired
//             stage(t+2 -> buf[t&1])           [issue 6 loads]
//   last iter peeled with vmcnt(0).
// sched_barrier(0) after every asm wait / raw barrier (guide rule #18).
// K hardcoded 2048. Grid 16x16 = 256 blocks = 1/CU (full machine, no
// fusion -> no R1 L2 blowup; per-XCD working set ~10 MB).
// mode 0: bf16 store (or fp32 if outf && *flag); 1: fused RoPE; 2: Vt.
// ---------------------------------------------------------------------------
#define SB2 (256 * 64)          // A-tile elements
#define SW2 (128 * 64)          // W-tile elements
#define SBUF2 (SB2 + SW2)       // one phase buffer = 24576 elems (48 KB)

__global__ __launch_bounds__(512) void gemm_nt2(const ushort_t* __restrict__ A,
                                                const ushort_t* __restrict__ W,
                                                ushort_t* __restrict__ C,
                                                float* __restrict__ outf,
                                                const int* __restrict__ flag,
                                                const float* __restrict__ rtab,
                                                int mode, int Ndim) {
    __shared__ ushort_t smem[2 * SBUF2];   // 96 KB
    const int tid  = threadIdx.x;
    const int lane = tid & 63;
    const int w    = tid >> 6;             // 0..7
    const int wr   = w >> 1;               // 0..3 : 64-row group
    const int wc   = w & 1;                // 0..1 : 64-col group
    const int quad = lane >> 4, l16 = lane & 15;
    const int Kd   = D_MODEL;

    // XCD-aware bijective swizzle, nwg = 256 (%8==0). bm-major per XCD.
    const int wg  = blockIdx.y * 16 + blockIdx.x;
    const int swz = (wg & 7) * 32 + (wg >> 3);
    const long bm = (long)(swz >> 4) * 256;
    const long bn = (long)(swz & 15) * 128;

    // Force the flag read to RETIRE before the pipeline starts, so the
    // vmcnt counting in the loop stays exact (no stray outstanding VMEM).
    int fl = *flag;
    asm volatile("" :: "v"(fl));
    asm volatile("s_waitcnt vmcnt(0)" ::: "memory");

    f32x4 acc[4][4];
    #pragma unroll
    for (int i = 0; i < 4; ++i)
        #pragma unroll
        for (int j = 0; j < 4; ++j) acc[i][j] = {0.f, 0.f, 0.f, 0.f};

    const int sw = l16 & 7;

    auto stage = [&](int kb, int buf) {
        ushort_t* As = smem + buf * SBUF2;
        ushort_t* Ws = As + SB2;
        #pragma unroll
        for (int i = 0; i < 4; ++i) {          // A: 256 rows, 4 loads/thread
            int ck = i * 512 + tid;
            int r = ck >> 3, g8 = (ck & 7) ^ (r & 7);
            g2l16(A + (bm + r) * Kd + kb + g8 * 8, As + (size_t)(i * 512 + w * 64) * 8);
        }
        #pragma unroll
        for (int i = 0; i < 2; ++i) {          // W: 128 rows, 2 loads/thread
            int ck = i * 512 + tid;
            int r = ck >> 3, g8 = (ck & 7) ^ (r & 7);
            g2l16(W + (bn + r) * Kd + kb + g8 * 8, Ws + (size_t)(i * 512 + w * 64) * 8);
        }
    };

    auto compute = [&](int buf) {
        const ushort_t* As = smem + buf * SBUF2;
        const ushort_t* Ws = As + SB2;
        #pragma unroll
        for (int kk2 = 0; kk2 < 2; ++kk2) {
            const int gb = kk2 * 4;
            bf16x8 af[4], bf[4];
            #pragma unroll
            for (int i = 0; i < 4; ++i)
                af[i] = *(const bf16x8*)(As + (wr * 64 + i * 16 + l16) * 64 + ((gb + quad) ^ sw) * 8);
            #pragma unroll
            for (int j = 0; j < 4; ++j)
                bf[j] = *(const bf16x8*)(Ws + (wc * 64 + j * 16 + l16) * 64 + ((gb + quad) ^ sw) * 8);
            #pragma unroll
            for (int i = 0; i < 4; ++i)
                #pragma unroll
                for (int j = 0; j < 4; ++j)
                    acc[i][j] = __builtin_amdgcn_mfma_f32_16x16x32_bf16(af[i], bf[j], acc[i][j], 0, 0, 0);
        }
    };

    stage(0, 0);
    stage(64, 1);
    for (int t = 0; t < 31; ++t) {
        asm volatile("s_waitcnt vmcnt(6)" ::: "memory");
        __builtin_amdgcn_sched_barrier(0);
        __builtin_amdgcn_s_barrier();
        __builtin_amdgcn_sched_barrier(0);
        compute(t & 1);
        asm volatile("s_waitcnt lgkmcnt(0)" ::: "memory");
        __builtin_amdgcn_sched_barrier(0);
        __builtin_amdgcn_s_barrier();
        __builtin_amdgcn_sched_barrier(0);
        if (t < 30) stage((t + 2) * 64, t & 1);
    }
    asm volatile("s_waitcnt vmcnt(0)" ::: "memory");
    __builtin_amdgcn_sched_barrier(0);
    __builtin_amdgcn_s_barrier();
    __builtin_amdgcn_sched_barrier(0);
    compute(1);
    __syncthreads();   // all reads retired before epilogue reuses smem

    if (mode == 2) {
        // Vt epilogue: transposed image [128 d][256 t] in LDS, store along t.
        #pragma unroll
        for (int i = 0; i < 4; ++i)
            #pragma unroll
            for (int j = 0; j < 4; ++j)
                #pragma unroll
                for (int r = 0; r < 4; ++r) {
                    int row = wr * 64 + i * 16 + quad * 4 + r;   // t in tile [0,256)
                    int col = wc * 64 + j * 16 + l16;            // d in head [0,128)
                    smem[col * 256 + ((((row >> 3) ^ (col & 7)) << 3) | (row & 7))] =
                        f2b(acc[i][j][r]);
                }
        __syncthreads();
        const int b = (int)(bm >> 11), t0 = (int)(bm & 2047), h = (int)(bn >> 7);
        const size_t obase = ((size_t)(b * NH + h) * HD) * T_SEQ;
        #pragma unroll
        for (int it = 0; it < 8; ++it) {
            int dd  = it * 16 + (tid >> 5);     // [0,128)
            int tch = tid & 31;                 // [0,32): 256 t / 8
            bf16x8 v = *(const bf16x8*)(smem + dd * 256 + ((tch ^ (dd & 7)) << 3));
            *(bf16x8*)(C + obase + (size_t)dd * T_SEQ + t0 + tch * 8) = v;
        }
        return;
    }

    const int as_f32 = (outf != nullptr) && (fl != 0);
    if (!as_f32) {
        // scatter full 256x128 bf16 image (64 KB)
        #pragma unroll
        for (int i = 0; i < 4; ++i)
            #pragma unroll
            for (int j = 0; j < 4; ++j)
                #pragma unroll
                for (int r = 0; r < 4; ++r) {
                    int row = wr * 64 + i * 16 + quad * 4 + r;
                    int col = wc * 64 + j * 16 + l16;
                    int ch = col >> 3, off = col & 7;
                    smem[row * 128 + (((ch ^ (row & 7)) << 3) | off)] = f2b(acc[i][j][r]);
                }
        __syncthreads();
        if (mode == 1) {
            #pragma unroll
            for (int it = 0; it < 8; ++it) {
                int row = it * 32 + (tid >> 4);   // [0,256)
                int ch  = tid & 15;
                int t = (int)((bm + row) & 2047);
                bf16x8 v = *(const bf16x8*)(smem + row * 128 + ((ch ^ (row & 7)) << 3));
                bf16x8 p = *(const bf16x8*)(smem + row * 128 + (((ch ^ 8) ^ (row & 7)) << 3));
                const float* cr = rtab + t * 128 + (ch & 7) * 8;
                float sgn = (ch < 8) ? -1.f : 1.f;
                union { ushort_t u[8]; float4 f[1]; } o;
                #pragma unroll
                for (int j = 0; j < 8; ++j) {
                    float cv = cr[j], sv = cr[64 + j];
                    o.u[j] = f2b(b2f(((const ushort_t*)&v)[j]) * cv +
                                 sgn * b2f(((const ushort_t*)&p)[j]) * sv);
                }
                *(bf16x8*)(C + (bm + row) * Ndim + bn + ch * 8) = *(const bf16x8*)o.u;
            }
        } else {
            #pragma unroll
            for (int it = 0; it < 8; ++it) {
                int row = it * 32 + (tid >> 4);
                int ch  = tid & 15;
                bf16x8 v = *(const bf16x8*)(smem + row * 128 + ((ch ^ (row & 7)) << 3));
                *(bf16x8*)(C + (bm + row) * Ndim + bn + ch * 8) = v;
            }
        }
    } else {
        // fp32 epilogue: two 128-row halves through 64 KB LDS
        float* Fs = (float*)smem;
        #pragma unroll
        for (int half = 0; half < 2; ++half) {
            __syncthreads();
            if ((wr >> 1) == half) {
                #pragma unroll
                for (int i = 0; i < 4; ++i)
                    #pragma unroll
                    for (int j = 0; j < 4; ++j)
                        #pragma unroll
                        for (int r = 0; r < 4; ++r) {
                            int lr = (wr & 1) * 64 + i * 16 + quad * 4 + r;  // [0,128)
                            int col = wc * 64 + j * 16 + l16;
                            int ch = col >> 2, off = col & 3;
                            Fs[lr * 128 + (((ch ^ (lr & 7)) << 2) | off)] = acc[i][j][r];
                        }
            }
            __syncthreads();
            #pragma unroll
            for (int it = 0; it < 8; ++it) {
                int lr = it * 16 + (tid >> 5);   // [0,128)
                int ch = tid & 31;
                float4 v = *(const float4*)(Fs + lr * 128 + ((ch ^ (lr & 7)) << 2));
                *(float4*)(outf + (bm + half * 128 + lr) * Ndim + bn + ch * 4) = v;
            }
        }
    }
}

// ---------------------------------------------------------------------------
// Causal flash attention — exact R3 kernel (87.6 us measured).
// R4 post-mortem: pairing q-tiles halved blocks/CU (4->2) and doubled VGPR;
// latency-bound kernel lost its inter-block TLP and regressed 38%. Keep the
// 1024-block 4/CU structure.
// ---------------------------------------------------------------------------
#define NQT (T_SEQ / 64)
#define C2SM 0.1275174452f   // 128^-0.5 * log2(e)
#define MFIX 96.0f

__global__ __launch_bounds__(256, 4) void attn_kernel(const ushort_t* __restrict__ Q,
                                                      const ushort_t* __restrict__ K,
                                                      const ushort_t* __restrict__ Vt,
                                                      ushort_t* __restrict__ O) {
    __shared__ ushort_t Ks[64 * 128];
    __shared__ ushort_t Vs[128 * 64];
    __shared__ ushort_t Ps[4 * 16 * 64];

    const int tid = threadIdx.x;
    const int lane = tid & 63, w = tid >> 6;
    const int quad = lane >> 4, l16 = lane & 15;
    const int bx = blockIdx.x;
    const int qb = (NQT - 1) - (bx >> 5);     // big tiles dispatch first
    const int bh = bx & 31;
    const int h = bh & 15, b = bh >> 4;

    const size_t qkbase = ((size_t)(b * T_SEQ)) * D_MODEL + h * HD;
    const size_t vtbase = ((size_t)((b * NH + h) * HD)) * T_SEQ;
    const int ck0 = w * 256 + lane;
    ushort_t* Pw = Ps + w * 1024;

    auto stage_K = [&](int kvb) {
        #pragma unroll
        for (int i = 0; i < 4; ++i) {
            int ck = ck0 + i * 64;
            int r = ck >> 4, g = (ck & 15) ^ (r & 15);
            g2l16(K + qkbase + (size_t)(kvb * 64 + r) * D_MODEL + g * 8,
                  (ushort_t*)Ks + (size_t)(w * 256 + i * 64) * 8);
        }
    };
    auto stage_V = [&](int kvb) {
        #pragma unroll
        for (int i = 0; i < 4; ++i) {
            int ck = ck0 + i * 64;
            int r = ck >> 3, g = (ck & 7) ^ (r & 7);
            g2l16(Vt + vtbase + (size_t)r * T_SEQ + kvb * 64 + g * 8,
                  (ushort_t*)Vs + (size_t)(w * 256 + i * 64) * 8);
        }
    };

    bf16x8 qf[4];
    {
        const ushort_t* qrow = Q + qkbase + (size_t)(qb * 64 + w * 16 + l16) * D_MODEL;
        #pragma unroll
        for (int ks = 0; ks < 4; ++ks)
            qf[ks] = *(const bf16x8*)(qrow + ks * 32 + quad * 8);
    }

    float l_i[4] = {0.f, 0.f, 0.f, 0.f};   // lane-partial; reduced at end
    f32x4 accO[8];
    for (int i = 0; i < 8; ++i) accO[i] = {0.f, 0.f, 0.f, 0.f};

    stage_K(0);                              // prologue

    for (int kvb = 0; kvb <= qb; ++kvb) {
        __syncthreads();                     // K(kvb) landed; Vs free
        stage_V(kvb);                        // in flight during QK^T+softmax

        f32x4 accS[4];
        for (int i = 0; i < 4; ++i) accS[i] = {0.f, 0.f, 0.f, 0.f};
        __builtin_amdgcn_s_setprio(1);
        #pragma unroll
        for (int ks = 0; ks < 4; ++ks) {
            #pragma unroll
            for (int ct = 0; ct < 4; ++ct) {
                bf16x8 bb = *(const bf16x8*)(Ks + (ct * 16 + l16) * 128 +
                                             (((ks * 4 + quad) ^ l16) * 8));
                accS[ct] = __builtin_amdgcn_mfma_f32_16x16x32_bf16(qf[ks], bb, accS[ct], 0, 0, 0);
            }
        }
        __builtin_amdgcn_s_setprio(0);

        if (kvb == qb) {   // diagonal: causal mask
            int qloc = w * 16 + quad * 4;
            for (int ct = 0; ct < 4; ++ct) {
                int key = ct * 16 + l16;
                for (int r = 0; r < 4; ++r)
                    if (key > qloc + r) accS[ct][r] = -1e30f;
            }
        }

        // p = exp2((s - M) * c); accumulate lane-partial l; store P to LDS
        #pragma unroll
        for (int ct = 0; ct < 4; ++ct) {
            #pragma unroll
            for (int r = 0; r < 4; ++r) {
                float pv = exp2f((accS[ct][r] - MFIX) * C2SM);
                l_i[r] += pv;
                int col = ct * 16 + l16;
                int row = quad * 4 + r;
                Pw[row * 64 + ((((col >> 3) ^ (row & 7)) << 3) | (col & 7))] = f2b(pv);
            }
        }

        __syncthreads();                     // V(kvb) landed; Ks free
        if (kvb < qb) stage_K(kvb + 1);      // in flight during PV

        __builtin_amdgcn_s_setprio(1);
        #pragma unroll
        for (int kk2 = 0; kk2 < 2; ++kk2) {
            bf16x8 a = *(const bf16x8*)(Pw + l16 * 64 + (((kk2 * 4 + quad) ^ (l16 & 7)) << 3));
            #pragma unroll
            for (int ct = 0; ct < 8; ++ct) {
                bf16x8 bb = *(const bf16x8*)(Vs + (ct * 16 + l16) * 64 +
                                             (((kk2 * 4 + quad) ^ (l16 & 7)) * 8));
                accO[ct] = __builtin_amdgcn_mfma_f32_16x16x32_bf16(a, bb, accO[ct], 0, 0, 0);
            }
        }
        __builtin_amdgcn_s_setprio(0);
    }

    // end-of-loop l reduction across the 16 lanes of each quad group
    #pragma unroll
    for (int r = 0; r < 4; ++r) {
        for (int off = 1; off < 16; off <<= 1)
            l_i[r] += __shfl_xor(l_i[r], off);
        l_i[r] = 1.f / l_i[r];
    }

    for (int ct = 0; ct < 8; ++ct)
        for (int r = 0; r < 4; ++r) {
            size_t row = (size_t)(b * T_SEQ + qb * 64 + w * 16 + quad * 4 + r);
            O[row * D_MODEL + h * HD + ct * 16 + l16] = f2b(accO[ct][r] * l_i[r]);
        }
}

// ---------------------------------------------------------------------------
extern "C" void kernel_launch(void* const* d_in, const int* in_sizes, int n_in,
                              void* d_out, int out_size, void* d_ws, size_t ws_size,
                              hipStream_t stream) {
    const size_t TEN = (size_t)M_ROWS * D_MODEL;
    const size_t WEL = (size_t)D_MODEL * D_MODEL;

    char* ws = (char*)d_ws;
    int* flag = (int*)ws;
    ushort_t* xb  = (ushort_t*)(ws + 256);
    ushort_t* Wqb = xb  + TEN;
    ushort_t* Wkb = Wqb + WEL;
    ushort_t* Wvb = Wkb + WEL;
    ushort_t* Wob = Wvb + WEL;
    ushort_t* Qb  = Wob + WEL;
    ushort_t* Kb  = Qb + TEN;
    ushort_t* attn = Kb + TEN;
    ushort_t* Vt  = attn + TEN;
    float* rtab = (float*)(Vt + TEN); // 2048*128 floats = 1 MB

    detect_dtype<<<1, 256, 0, stream>>>((const ushort_t*)d_in[0], flag);
    rope_table<<<(T_SEQ * 64) / 256, 256, 0, stream>>>(rtab);
    convert_all<<<(int)((TEN + 4 * WEL) / 8 / 256), 256, 0, stream>>>(
        d_in[0], d_in[1], d_in[2], d_in[3], d_in[4], xb, flag);

    dim3 gg(16, 16);   // N/128 x M/256 = 256 blocks = 1/CU
    gemm_nt2<<<gg, 512, 0, stream>>>(xb, Wqb, Qb, nullptr, flag, rtab, 1, D_MODEL);
    gemm_nt2<<<gg, 512, 0, stream>>>(xb, Wkb, Kb, nullptr, flag, rtab, 1, D_MODEL);
    gemm_nt2<<<gg, 512, 0, stream>>>(xb, Wvb, Vt, nullptr, flag, rtab, 2, D_MODEL);
    attn_kernel<<<dim3(NQT * NB * NH), 256, 0, stream>>>(Qb, Kb, Vt, attn);
    gemm_nt2<<<gg, 512, 0, stream>>>(attn, Wob, (ushort_t*)d_out, (float*)d_out, flag,
                                     rtab, 0, D_MODEL);
}

// Round 6
// 377.310 us; speedup vs baseline: 1.1103x; 1.0104x over previous
//
#include <hip/hip_runtime.h>

typedef unsigned short ushort_t;
typedef short bf16x8 __attribute__((ext_vector_type(8)));
typedef float f32x4 __attribute__((ext_vector_type(4)));

#define D_MODEL 2048
#define T_SEQ 2048
#define NB 2
#define NH 16
#define HD 128
#define M_ROWS 4096

__device__ __forceinline__ float b2f(unsigned short u) {
    return __uint_as_float(((unsigned)u) << 16);
}
__device__ __forceinline__ unsigned short f2b(float f) {
    unsigned u = __float_as_uint(f);
    u += 0x7fffu + ((u >> 16) & 1u);
    return (unsigned short)(u >> 16);
}

// async global->LDS, 16B per lane. lds base must be wave-uniform.
__device__ __forceinline__ void g2l16(const ushort_t* g, ushort_t* l) {
    __builtin_amdgcn_global_load_lds(
        (const __attribute__((address_space(1))) unsigned int*)g,
        (__attribute__((address_space(3))) unsigned int*)l, 16, 0, 0);
}

// ---------------------------------------------------------------------------
// Input dtype probe (1 = fp32 inputs).
// ---------------------------------------------------------------------------
__global__ void detect_dtype(const ushort_t* __restrict__ x, int* __restrict__ flag) {
    __shared__ int cnt;
    if (threadIdx.x == 0) cnt = 0;
    __syncthreads();
    int c = 0;
    for (int i = threadIdx.x; i < 8192; i += 256) {
        int e = (x[i] >> 7) & 0xFF;
        if (e >= 0xC8) ++c;
    }
    atomicAdd(&cnt, c);
    __syncthreads();
    if (threadIdx.x == 0) *flag = (cnt > 16) ? 1 : 0;
}

// ---------------------------------------------------------------------------
// One fused conversion pass for x + 4 weight matrices.
// ---------------------------------------------------------------------------
__global__ void convert_all(const void* __restrict__ s0, const void* __restrict__ s1,
                            const void* __restrict__ s2, const void* __restrict__ s3,
                            const void* __restrict__ s4, ushort_t* __restrict__ dst,
                            const int* __restrict__ flag) {
    const size_t TENc = (size_t)M_ROWS * D_MODEL;   // 2^23
    const size_t WELc = (size_t)D_MODEL * D_MODEL;  // 2^22
    size_t i = ((size_t)blockIdx.x * 256 + threadIdx.x) * 8;
    const void* src;
    size_t off;
    if (i < TENc) {
        src = s0; off = i;
    } else {
        size_t j = i - TENc;
        int wsel = (int)(j >> 22);
        src = (wsel == 0) ? s1 : (wsel == 1) ? s2 : (wsel == 2) ? s3 : s4;
        off = j & (WELc - 1);
    }
    if (*flag) {
        const float* s = (const float*)src + off;
        union { ushort_t u[8]; float4 f; } pk;
        #pragma unroll
        for (int j2 = 0; j2 < 8; ++j2) pk.u[j2] = f2b(s[j2]);
        *(float4*)(dst + i) = pk.f;
    } else {
        *(float4*)(dst + i) = *(const float4*)((const ushort_t*)src + off);
    }
}

// ---------------------------------------------------------------------------
// RoPE cos/sin table: tab[t*128 + i] = cos(t*invf(i)), tab[t*128+64+i] = sin.
// ---------------------------------------------------------------------------
__global__ void rope_table(float* __restrict__ tab) {
    int tid = blockIdx.x * 256 + threadIdx.x;   // t*64 + i
    int i = tid & 63, t = tid >> 6;
    float ang = (float)t * exp2f(-(float)i * 0.20762050593046015f);
    tab[t * 128 + i]      = cosf(ang);
    tab[t * 128 + 64 + i] = sinf(ang);
}

// ---------------------------------------------------------------------------
// R6 GEMM: 256x128 tile, 512 threads (8 waves, 4Mx2N, per-wave 64x64),
// FINE-INTERLEAVED pipeline (T3+T4 proper): BK=32 steps, 4 LDS buffers,
// ONE barrier per step, counted vmcnt, load issue 3 steps ahead.
//   step s: s_waitcnt vmcnt(6)   [stage(s) landed; s+1,s+2 in flight]
//           s_barrier             [collective: buf(s) ready; buf((s+3)&3)'s
//                                  readers all finished last step]
//           issue stage(s+3)      [3 global_load_lds, fly across barriers]
//           8 ds_read -> 16 MFMA (setprio-wrapped)
// Hazards: RAW via vmcnt+barrier; WAR because stage(s+3) is issued after
// the barrier that follows all reads of buf((s+3)&3) (compiler lgkm waits
// retire reads before each wave's MFMAs). sched_barrier(0) after asm waits
// and barriers (rule #18).
// LDS layout per buffer: A[256][32] | W[128][32], chunk slot = c ^ ((row>>1)&3)
// (both-sides swizzle; ds_read pattern verified <=2-way per quarter-wave).
// Grid 16x16 = 256 blocks = 1/CU. LDS 96KB. K hardcoded 2048 = 64 steps.
// mode 0: bf16 store (or fp32 if outf && *flag); 1: fused RoPE; 2: Vt.
// ---------------------------------------------------------------------------
#define ABUF3 (256 * 32)          // 8192 elems
#define WBUF3 (128 * 32)          // 4096 elems
#define PBUF3 (ABUF3 + WBUF3)     // 12288 elems = 24 KB per buffer

__global__ __launch_bounds__(512) void gemm_nt3(const ushort_t* __restrict__ A,
                                                const ushort_t* __restrict__ W,
                                                ushort_t* __restrict__ C,
                                                float* __restrict__ outf,
                                                const int* __restrict__ flag,
                                                const float* __restrict__ rtab,
                                                int mode, int Ndim) {
    __shared__ ushort_t smem[4 * PBUF3];   // 96 KB
    const int tid  = threadIdx.x;
    const int lane = tid & 63;
    const int w    = tid >> 6;             // 0..7
    const int wr   = w >> 1;               // 0..3 : 64-row group
    const int wc   = w & 1;                // 0..1 : 64-col group
    const int quad = lane >> 4, l16 = lane & 15;
    const int Kd   = D_MODEL;

    // XCD-aware bijective swizzle, nwg = 256 (%8==0).
    const int wg  = blockIdx.y * 16 + blockIdx.x;
    const int swz = (wg & 7) * 32 + (wg >> 3);
    const long bm = (long)(swz >> 4) * 256;
    const long bn = (long)(swz & 15) * 128;

    // Retire the flag read before the pipeline so vmcnt counting is exact.
    int fl = *flag;
    asm volatile("" :: "v"(fl));
    asm volatile("s_waitcnt vmcnt(0)" ::: "memory");

    f32x4 acc[4][4];
    #pragma unroll
    for (int i = 0; i < 4; ++i)
        #pragma unroll
        for (int j = 0; j < 4; ++j) acc[i][j] = {0.f, 0.f, 0.f, 0.f};

    // staging thread mapping: per K-step (32 elems) each thread does
    // 2 A-loads + 1 W-load of 16B. Wave-instruction j covers 16 rows (1KB).
    const int lr = lane >> 2;              // row within 16-row group
    const int cl = lane & 3;               // 16B chunk within 64B row
    const int rowA0 = (w * 2 + 0) * 16 + lr;
    const int rowA1 = (w * 2 + 1) * 16 + lr;
    const int rowW  = w * 16 + lr;
    // pre-swizzled global sources: LDS slot cl holds global chunk cl^f(row)
    const ushort_t* gA0 = A + (bm + rowA0) * Kd + ((cl ^ ((rowA0 >> 1) & 3)) * 8);
    const ushort_t* gA1 = A + (bm + rowA1) * Kd + ((cl ^ ((rowA1 >> 1) & 3)) * 8);
    const ushort_t* gW  = W + (bn + rowW)  * Kd + ((cl ^ ((rowW  >> 1) & 3)) * 8);

    const int fsl = (l16 >> 1) & 3;        // read-side swizzle

    auto stage = [&](int s) {
        ushort_t* As = smem + (s & 3) * PBUF3;
        ushort_t* Ws = As + ABUF3;
        const int ko = s * 32;
        g2l16(gA0 + ko, As + (w * 2 + 0) * 512);
        g2l16(gA1 + ko, As + (w * 2 + 1) * 512);
        g2l16(gW + ko, Ws + w * 512);
    };

    auto kstep = [&](int s, int vm, bool do_stage) {
        if (vm == 6)      asm volatile("s_waitcnt vmcnt(6)" ::: "memory");
        else if (vm == 3) asm volatile("s_waitcnt vmcnt(3)" ::: "memory");
        else              asm volatile("s_waitcnt vmcnt(0)" ::: "memory");
        __builtin_amdgcn_sched_barrier(0);
        __builtin_amdgcn_s_barrier();
        __builtin_amdgcn_sched_barrier(0);
        if (do_stage) stage(s + 3);
        const ushort_t* As = smem + (s & 3) * PBUF3;
        const ushort_t* Ws = As + ABUF3;
        bf16x8 af[4], bf[4];
        #pragma unroll
        for (int i = 0; i < 4; ++i)
            af[i] = *(const bf16x8*)(As + (wr * 64 + i * 16 + l16) * 32 + (quad ^ fsl) * 8);
        #pragma unroll
        for (int j = 0; j < 4; ++j)
            bf[j] = *(const bf16x8*)(Ws + (wc * 64 + j * 16 + l16) * 32 + (quad ^ fsl) * 8);
        __builtin_amdgcn_s_setprio(1);
        #pragma unroll
        for (int i = 0; i < 4; ++i)
            #pragma unroll
            for (int j = 0; j < 4; ++j)
                acc[i][j] = __builtin_amdgcn_mfma_f32_16x16x32_bf16(af[i], bf[j], acc[i][j], 0, 0, 0);
        __builtin_amdgcn_s_setprio(0);
    };

    stage(0); stage(1); stage(2);          // 9 loads in flight
    #pragma unroll 4
    for (int s = 0; s < 60; ++s) kstep(s, 6, true);   // stages up to 62
    kstep(60, 6, true);                    // stages 63
    kstep(61, 6, false);
    kstep(62, 3, false);
    kstep(63, 0, false);
    __syncthreads();   // all LDS reads retired before epilogue reuses smem

    if (mode == 2) {
        // Vt epilogue: transposed image [128 d][256 t] in LDS, store along t.
        #pragma unroll
        for (int i = 0; i < 4; ++i)
            #pragma unroll
            for (int j = 0; j < 4; ++j)
                #pragma unroll
                for (int r = 0; r < 4; ++r) {
                    int row = wr * 64 + i * 16 + quad * 4 + r;   // t in tile [0,256)
                    int col = wc * 64 + j * 16 + l16;            // d in head [0,128)
                    smem[col * 256 + ((((row >> 3) ^ (col & 7)) << 3) | (row & 7))] =
                        f2b(acc[i][j][r]);
                }
        __syncthreads();
        const int b = (int)(bm >> 11), t0 = (int)(bm & 2047), h = (int)(bn >> 7);
        const size_t obase = ((size_t)(b * NH + h) * HD) * T_SEQ;
        #pragma unroll
        for (int it = 0; it < 8; ++it) {
            int dd  = it * 16 + (tid >> 5);     // [0,128)
            int tch = tid & 31;                 // [0,32): 256 t / 8
            bf16x8 v = *(const bf16x8*)(smem + dd * 256 + ((tch ^ (dd & 7)) << 3));
            *(bf16x8*)(C + obase + (size_t)dd * T_SEQ + t0 + tch * 8) = v;
        }
        return;
    }

    const int as_f32 = (outf != nullptr) && (fl != 0);
    if (!as_f32) {
        // scatter full 256x128 bf16 image (64 KB)
        #pragma unroll
        for (int i = 0; i < 4; ++i)
            #pragma unroll
            for (int j = 0; j < 4; ++j)
                #pragma unroll
                for (int r = 0; r < 4; ++r) {
                    int row = wr * 64 + i * 16 + quad * 4 + r;
                    int col = wc * 64 + j * 16 + l16;
                    int ch = col >> 3, off = col & 7;
                    smem[row * 128 + (((ch ^ (row & 7)) << 3) | off)] = f2b(acc[i][j][r]);
                }
        __syncthreads();
        if (mode == 1) {
            #pragma unroll
            for (int it = 0; it < 8; ++it) {
                int row = it * 32 + (tid >> 4);   // [0,256)
                int ch  = tid & 15;
                int t = (int)((bm + row) & 2047);
                bf16x8 v = *(const bf16x8*)(smem + row * 128 + ((ch ^ (row & 7)) << 3));
                bf16x8 p = *(const bf16x8*)(smem + row * 128 + (((ch ^ 8) ^ (row & 7)) << 3));
                const float* cr = rtab + t * 128 + (ch & 7) * 8;
                float sgn = (ch < 8) ? -1.f : 1.f;
                union { ushort_t u[8]; float4 f[1]; } o;
                #pragma unroll
                for (int j = 0; j < 8; ++j) {
                    float cv = cr[j], sv = cr[64 + j];
                    o.u[j] = f2b(b2f(((const ushort_t*)&v)[j]) * cv +
                                 sgn * b2f(((const ushort_t*)&p)[j]) * sv);
                }
                *(bf16x8*)(C + (bm + row) * Ndim + bn + ch * 8) = *(const bf16x8*)o.u;
            }
        } else {
            #pragma unroll
            for (int it = 0; it < 8; ++it) {
                int row = it * 32 + (tid >> 4);
                int ch  = tid & 15;
                bf16x8 v = *(const bf16x8*)(smem + row * 128 + ((ch ^ (row & 7)) << 3));
                *(bf16x8*)(C + (bm + row) * Ndim + bn + ch * 8) = v;
            }
        }
    } else {
        // fp32 epilogue: two 128-row halves through 64 KB LDS
        float* Fs = (float*)smem;
        #pragma unroll
        for (int half = 0; half < 2; ++half) {
            __syncthreads();
            if ((wr >> 1) == half) {
                #pragma unroll
                for (int i = 0; i < 4; ++i)
                    #pragma unroll
                    for (int j = 0; j < 4; ++j)
                        #pragma unroll
                        for (int r = 0; r < 4; ++r) {
                            int lrow = (wr & 1) * 64 + i * 16 + quad * 4 + r;  // [0,128)
                            int col = wc * 64 + j * 16 + l16;
                            int ch = col >> 2, off = col & 3;
                            Fs[lrow * 128 + (((ch ^ (lrow & 7)) << 2) | off)] = acc[i][j][r];
                        }
            }
            __syncthreads();
            #pragma unroll
            for (int it = 0; it < 8; ++it) {
                int lrow = it * 16 + (tid >> 5);   // [0,128)
                int ch = tid & 31;
                float4 v = *(const float4*)(Fs + lrow * 128 + ((ch ^ (lrow & 7)) << 2));
                *(float4*)(outf + (bm + half * 128 + lrow) * Ndim + bn + ch * 4) = v;
            }
        }
    }
}

// ---------------------------------------------------------------------------
// Causal flash attention — R3 structure (87.6 us) + R6 CU-draw balancing.
// Blocks round-robin to CUs as {c, c+256, c+512, c+768}; remap g=bx>>5 -> qb
// so each CU draw sums to a constant 62 iters (was 52..80 -> ~20% tail):
//   g in [0,8): 31-g | [8,16): g-8 | [16,24): 39-g | [24,32): g-16
// Bijective; big tiles still dispatch first. R4 lesson kept: 1024 blocks,
// 4/CU, 64 VGPR — do not trade TLP for per-block work.
// ---------------------------------------------------------------------------
#define NQT (T_SEQ / 64)
#define C2SM 0.1275174452f   // 128^-0.5 * log2(e)
#define MFIX 96.0f

__global__ __launch_bounds__(256, 4) void attn_kernel(const ushort_t* __restrict__ Q,
                                                      const ushort_t* __restrict__ K,
                                                      const ushort_t* __restrict__ Vt,
                                                      ushort_t* __restrict__ O) {
    __shared__ ushort_t Ks[64 * 128];
    __shared__ ushort_t Vs[128 * 64];
    __shared__ ushort_t Ps[4 * 16 * 64];

    const int tid = threadIdx.x;
    const int lane = tid & 63, w = tid >> 6;
    const int quad = lane >> 4, l16 = lane & 15;
    const int bx = blockIdx.x;
    const int g = bx >> 5;
    int qb;
    if (g < 8)       qb = 31 - g;
    else if (g < 16) qb = g - 8;
    else if (g < 24) qb = 39 - g;
    else             qb = g - 16;
    const int bh = bx & 31;
    const int h = bh & 15, b = bh >> 4;

    const size_t qkbase = ((size_t)(b * T_SEQ)) * D_MODEL + h * HD;
    const size_t vtbase = ((size_t)((b * NH + h) * HD)) * T_SEQ;
    const int ck0 = w * 256 + lane;
    ushort_t* Pw = Ps + w * 1024;

    auto stage_K = [&](int kvb) {
        #pragma unroll
        for (int i = 0; i < 4; ++i) {
            int ck = ck0 + i * 64;
            int r = ck >> 4, gg = (ck & 15) ^ (r & 15);
            g2l16(K + qkbase + (size_t)(kvb * 64 + r) * D_MODEL + gg * 8,
                  (ushort_t*)Ks + (size_t)(w * 256 + i * 64) * 8);
        }
    };
    auto stage_V = [&](int kvb) {
        #pragma unroll
        for (int i = 0; i < 4; ++i) {
            int ck = ck0 + i * 64;
            int r = ck >> 3, gg = (ck & 7) ^ (r & 7);
            g2l16(Vt + vtbase + (size_t)r * T_SEQ + kvb * 64 + gg * 8,
                  (ushort_t*)Vs + (size_t)(w * 256 + i * 64) * 8);
        }
    };

    bf16x8 qf[4];
    {
        const ushort_t* qrow = Q + qkbase + (size_t)(qb * 64 + w * 16 + l16) * D_MODEL;
        #pragma unroll
        for (int ks = 0; ks < 4; ++ks)
            qf[ks] = *(const bf16x8*)(qrow + ks * 32 + quad * 8);
    }

    float l_i[4] = {0.f, 0.f, 0.f, 0.f};   // lane-partial; reduced at end
    f32x4 accO[8];
    for (int i = 0; i < 8; ++i) accO[i] = {0.f, 0.f, 0.f, 0.f};

    stage_K(0);                              // prologue

    for (int kvb = 0; kvb <= qb; ++kvb) {
        __syncthreads();                     // K(kvb) landed; Vs free
        stage_V(kvb);                        // in flight during QK^T+softmax

        f32x4 accS[4];
        for (int i = 0; i < 4; ++i) accS[i] = {0.f, 0.f, 0.f, 0.f};
        __builtin_amdgcn_s_setprio(1);
        #pragma unroll
        for (int ks = 0; ks < 4; ++ks) {
            #pragma unroll
            for (int ct = 0; ct < 4; ++ct) {
                bf16x8 bb = *(const bf16x8*)(Ks + (ct * 16 + l16) * 128 +
                                             (((ks * 4 + quad) ^ l16) * 8));
                accS[ct] = __builtin_amdgcn_mfma_f32_16x16x32_bf16(qf[ks], bb, accS[ct], 0, 0, 0);
            }
        }
        __builtin_amdgcn_s_setprio(0);

        if (kvb == qb) {   // diagonal: causal mask
            int qloc = w * 16 + quad * 4;
            for (int ct = 0; ct < 4; ++ct) {
                int key = ct * 16 + l16;
                for (int r = 0; r < 4; ++r)
                    if (key > qloc + r) accS[ct][r] = -1e30f;
            }
        }

        // p = exp2((s - M) * c); accumulate lane-partial l; store P to LDS
        #pragma unroll
        for (int ct = 0; ct < 4; ++ct) {
            #pragma unroll
            for (int r = 0; r < 4; ++r) {
                float pv = exp2f((accS[ct][r] - MFIX) * C2SM);
                l_i[r] += pv;
                int col = ct * 16 + l16;
                int row = quad * 4 + r;
                Pw[row * 64 + ((((col >> 3) ^ (row & 7)) << 3) | (col & 7))] = f2b(pv);
            }
        }

        __syncthreads();                     // V(kvb) landed; Ks free
        if (kvb < qb) stage_K(kvb + 1);      // in flight during PV

        __builtin_amdgcn_s_setprio(1);
        #pragma unroll
        for (int kk2 = 0; kk2 < 2; ++kk2) {
            bf16x8 a = *(const bf16x8*)(Pw + l16 * 64 + (((kk2 * 4 + quad) ^ (l16 & 7)) << 3));
            #pragma unroll
            for (int ct = 0; ct < 8; ++ct) {
                bf16x8 bb = *(const bf16x8*)(Vs + (ct * 16 + l16) * 64 +
                                             (((kk2 * 4 + quad) ^ (l16 & 7)) * 8));
                accO[ct] = __builtin_amdgcn_mfma_f32_16x16x32_bf16(a, bb, accO[ct], 0, 0, 0);
            }
        }
        __builtin_amdgcn_s_setprio(0);
    }

    // end-of-loop l reduction across the 16 lanes of each quad group
    #pragma unroll
    for (int r = 0; r < 4; ++r) {
        for (int off = 1; off < 16; off <<= 1)
            l_i[r] += __shfl_xor(l_i[r], off);
        l_i[r] = 1.f / l_i[r];
    }

    for (int ct = 0; ct < 8; ++ct)
        for (int r = 0; r < 4; ++r) {
            size_t row = (size_t)(b * T_SEQ + qb * 64 + w * 16 + quad * 4 + r);
            O[row * D_MODEL + h * HD + ct * 16 + l16] = f2b(accO[ct][r] * l_i[r]);
        }
}

// ---------------------------------------------------------------------------
extern "C" void kernel_launch(void* const* d_in, const int* in_sizes, int n_in,
                              void* d_out, int out_size, void* d_ws, size_t ws_size,
                              hipStream_t stream) {
    const size_t TEN = (size_t)M_ROWS * D_MODEL;
    const size_t WEL = (size_t)D_MODEL * D_MODEL;

    char* ws = (char*)d_ws;
    int* flag = (int*)ws;
    ushort_t* xb  = (ushort_t*)(ws + 256);
    ushort_t* Wqb = xb  + TEN;
    ushort_t* Wkb = Wqb + WEL;
    ushort_t* Wvb = Wkb + WEL;
    ushort_t* Wob = Wvb + WEL;
    ushort_t* Qb  = Wob + WEL;
    ushort_t* Kb  = Qb + TEN;
    ushort_t* attn = Kb + TEN;
    ushort_t* Vt  = attn + TEN;
    float* rtab = (float*)(Vt + TEN); // 2048*128 floats = 1 MB

    detect_dtype<<<1, 256, 0, stream>>>((const ushort_t*)d_in[0], flag);
    rope_table<<<(T_SEQ * 64) / 256, 256, 0, stream>>>(rtab);
    convert_all<<<(int)((TEN + 4 * WEL) / 8 / 256), 256, 0, stream>>>(
        d_in[0], d_in[1], d_in[2], d_in[3], d_in[4], xb, flag);

    dim3 gg(16, 16);   // N/128 x M/256 = 256 blocks = 1/CU
    gemm_nt3<<<gg, 512, 0, stream>>>(xb, Wqb, Qb, nullptr, flag, rtab, 1, D_MODEL);
    gemm_nt3<<<gg, 512, 0, stream>>>(xb, Wkb, Kb, nullptr, flag, rtab, 1, D_MODEL);
    gemm_nt3<<<gg, 512, 0, stream>>>(xb, Wvb, Vt, nullptr, flag, rtab, 2, D_MODEL);
    attn_kernel<<<dim3(NQT * NB * NH), 256, 0, stream>>>(Qb, Kb, Vt, attn);
    gemm_nt3<<<gg, 512, 0, stream>>>(attn, Wob, (ushort_t*)d_out, (float*)d_out, flag,
                                     rtab, 0, D_MODEL);
}

// Round 7
// 369.248 us; speedup vs baseline: 1.1345x; 1.0218x over previous
//
#include <hip/hip_runtime.h>

typedef unsigned short ushort_t;
typedef short bf16x8 __attribute__((ext_vector_type(8)));
typedef float f32x4 __attribute__((ext_vector_type(4)));

#define D_MODEL 2048
#define T_SEQ 2048
#define NB 2
#define NH 16
#define HD 128
#define M_ROWS 4096

__device__ __forceinline__ float b2f(unsigned short u) {
    return __uint_as_float(((unsigned)u) << 16);
}
__device__ __forceinline__ unsigned short f2b(float f) {
    unsigned u = __float_as_uint(f);
    u += 0x7fffu + ((u >> 16) & 1u);
    return (unsigned short)(u >> 16);
}

// async global->LDS, 16B per lane. lds base must be wave-uniform.
__device__ __forceinline__ void g2l16(const ushort_t* g, ushort_t* l) {
    __builtin_amdgcn_global_load_lds(
        (const __attribute__((address_space(1))) unsigned int*)g,
        (__attribute__((address_space(3))) unsigned int*)l, 16, 0, 0);
}

// ---------------------------------------------------------------------------
// Input dtype probe (1 = fp32 inputs).
// ---------------------------------------------------------------------------
__global__ void detect_dtype(const ushort_t* __restrict__ x, int* __restrict__ flag) {
    __shared__ int cnt;
    if (threadIdx.x == 0) cnt = 0;
    __syncthreads();
    int c = 0;
    for (int i = threadIdx.x; i < 8192; i += 256) {
        int e = (x[i] >> 7) & 0xFF;
        if (e >= 0xC8) ++c;
    }
    atomicAdd(&cnt, c);
    __syncthreads();
    if (threadIdx.x == 0) *flag = (cnt > 16) ? 1 : 0;
}

// ---------------------------------------------------------------------------
// One fused conversion pass for x + 4 weight matrices.
// ---------------------------------------------------------------------------
__global__ void convert_all(const void* __restrict__ s0, const void* __restrict__ s1,
                            const void* __restrict__ s2, const void* __restrict__ s3,
                            const void* __restrict__ s4, ushort_t* __restrict__ dst,
                            const int* __restrict__ flag) {
    const size_t TENc = (size_t)M_ROWS * D_MODEL;   // 2^23
    const size_t WELc = (size_t)D_MODEL * D_MODEL;  // 2^22
    size_t i = ((size_t)blockIdx.x * 256 + threadIdx.x) * 8;
    const void* src;
    size_t off;
    if (i < TENc) {
        src = s0; off = i;
    } else {
        size_t j = i - TENc;
        int wsel = (int)(j >> 22);
        src = (wsel == 0) ? s1 : (wsel == 1) ? s2 : (wsel == 2) ? s3 : s4;
        off = j & (WELc - 1);
    }
    if (*flag) {
        const float* s = (const float*)src + off;
        union { ushort_t u[8]; float4 f; } pk;
        #pragma unroll
        for (int j2 = 0; j2 < 8; ++j2) pk.u[j2] = f2b(s[j2]);
        *(float4*)(dst + i) = pk.f;
    } else {
        *(float4*)(dst + i) = *(const float4*)((const ushort_t*)src + off);
    }
}

// ---------------------------------------------------------------------------
// RoPE cos/sin table: tab[t*128 + i] = cos(t*invf(i)), tab[t*128+64+i] = sin.
// ---------------------------------------------------------------------------
__global__ void rope_table(float* __restrict__ tab) {
    int tid = blockIdx.x * 256 + threadIdx.x;   // t*64 + i
    int i = tid & 63, t = tid >> 6;
    float ang = (float)t * exp2f(-(float)i * 0.20762050593046015f);
    tab[t * 128 + i]      = cosf(ang);
    tab[t * 128 + 64 + i] = sinf(ang);
}

// ---------------------------------------------------------------------------
// R6 GEMM body: 256x128 tile, 512 threads (8 waves, 4Mx2N, per-wave 64x64),
// fine-interleaved counted-vmcnt pipeline, BK=32, 4 LDS buffers.
// R5/R6 post-mortem: 2-phase, coarse-counted and fine-counted schedules all
// measure ~64us/GEMM -> K-loop schedule is NOT the binding constraint at
// this shape; stop pipelining on hypothesis (rule: pivot after 2 nulls).
// mode 0: bf16 store (or fp32 if outf && *flag); 1: fused RoPE; 2: Vt.
// ---------------------------------------------------------------------------
#define ABUF3 (256 * 32)          // 8192 elems
#define WBUF3 (128 * 32)          // 4096 elems
#define PBUF3 (ABUF3 + WBUF3)     // 12288 elems = 24 KB per buffer

__device__ __forceinline__ void gemm3_body(const ushort_t* __restrict__ A,
                                           const ushort_t* __restrict__ W,
                                           ushort_t* __restrict__ C,
                                           float* __restrict__ outf,
                                           int fl,
                                           const float* __restrict__ rtab,
                                           int mode, int Ndim,
                                           long bm, long bn,
                                           ushort_t* smem) {
    const int tid  = threadIdx.x;
    const int lane = tid & 63;
    const int w    = tid >> 6;             // 0..7
    const int wr   = w >> 1;               // 0..3 : 64-row group
    const int wc   = w & 1;                // 0..1 : 64-col group
    const int quad = lane >> 4, l16 = lane & 15;
    const int Kd   = D_MODEL;

    f32x4 acc[4][4];
    #pragma unroll
    for (int i = 0; i < 4; ++i)
        #pragma unroll
        for (int j = 0; j < 4; ++j) acc[i][j] = {0.f, 0.f, 0.f, 0.f};

    // staging thread mapping: per K-step (32 elems) each thread does
    // 2 A-loads + 1 W-load of 16B. Wave-instruction j covers 16 rows (1KB).
    const int lr = lane >> 2;              // row within 16-row group
    const int cl = lane & 3;               // 16B chunk within 64B row
    const int rowA0 = (w * 2 + 0) * 16 + lr;
    const int rowA1 = (w * 2 + 1) * 16 + lr;
    const int rowW  = w * 16 + lr;
    // pre-swizzled global sources: LDS slot cl holds global chunk cl^f(row)
    const ushort_t* gA0 = A + (bm + rowA0) * Kd + ((cl ^ ((rowA0 >> 1) & 3)) * 8);
    const ushort_t* gA1 = A + (bm + rowA1) * Kd + ((cl ^ ((rowA1 >> 1) & 3)) * 8);
    const ushort_t* gW  = W + (bn + rowW)  * Kd + ((cl ^ ((rowW  >> 1) & 3)) * 8);

    const int fsl = (l16 >> 1) & 3;        // read-side swizzle

    auto stage = [&](int s) {
        ushort_t* As = smem + (s & 3) * PBUF3;
        ushort_t* Ws = As + ABUF3;
        const int ko = s * 32;
        g2l16(gA0 + ko, As + (w * 2 + 0) * 512);
        g2l16(gA1 + ko, As + (w * 2 + 1) * 512);
        g2l16(gW + ko, Ws + w * 512);
    };

    auto kstep = [&](int s, int vm, bool do_stage) {
        if (vm == 6)      asm volatile("s_waitcnt vmcnt(6)" ::: "memory");
        else if (vm == 3) asm volatile("s_waitcnt vmcnt(3)" ::: "memory");
        else              asm volatile("s_waitcnt vmcnt(0)" ::: "memory");
        __builtin_amdgcn_sched_barrier(0);
        __builtin_amdgcn_s_barrier();
        __builtin_amdgcn_sched_barrier(0);
        if (do_stage) stage(s + 3);
        const ushort_t* As = smem + (s & 3) * PBUF3;
        const ushort_t* Ws = As + ABUF3;
        bf16x8 af[4], bf[4];
        #pragma unroll
        for (int i = 0; i < 4; ++i)
            af[i] = *(const bf16x8*)(As + (wr * 64 + i * 16 + l16) * 32 + (quad ^ fsl) * 8);
        #pragma unroll
        for (int j = 0; j < 4; ++j)
            bf[j] = *(const bf16x8*)(Ws + (wc * 64 + j * 16 + l16) * 32 + (quad ^ fsl) * 8);
        __builtin_amdgcn_s_setprio(1);
        #pragma unroll
        for (int i = 0; i < 4; ++i)
            #pragma unroll
            for (int j = 0; j < 4; ++j)
                acc[i][j] = __builtin_amdgcn_mfma_f32_16x16x32_bf16(af[i], bf[j], acc[i][j], 0, 0, 0);
        __builtin_amdgcn_s_setprio(0);
    };

    stage(0); stage(1); stage(2);          // 9 loads in flight
    #pragma unroll 4
    for (int s = 0; s < 60; ++s) kstep(s, 6, true);   // stages up to 62
    kstep(60, 6, true);                    // stages 63
    kstep(61, 6, false);
    kstep(62, 3, false);
    kstep(63, 0, false);
    __syncthreads();   // all LDS reads retired before epilogue reuses smem

    if (mode == 2) {
        // Vt epilogue: transposed image [128 d][256 t] in LDS, store along t.
        #pragma unroll
        for (int i = 0; i < 4; ++i)
            #pragma unroll
            for (int j = 0; j < 4; ++j)
                #pragma unroll
                for (int r = 0; r < 4; ++r) {
                    int row = wr * 64 + i * 16 + quad * 4 + r;   // t in tile [0,256)
                    int col = wc * 64 + j * 16 + l16;            // d in head [0,128)
                    smem[col * 256 + ((((row >> 3) ^ (col & 7)) << 3) | (row & 7))] =
                        f2b(acc[i][j][r]);
                }
        __syncthreads();
        const int b = (int)(bm >> 11), t0 = (int)(bm & 2047), h = (int)(bn >> 7);
        const size_t obase = ((size_t)(b * NH + h) * HD) * T_SEQ;
        #pragma unroll
        for (int it = 0; it < 8; ++it) {
            int dd  = it * 16 + (tid >> 5);     // [0,128)
            int tch = tid & 31;                 // [0,32): 256 t / 8
            bf16x8 v = *(const bf16x8*)(smem + dd * 256 + ((tch ^ (dd & 7)) << 3));
            *(bf16x8*)(C + obase + (size_t)dd * T_SEQ + t0 + tch * 8) = v;
        }
        return;
    }

    const int as_f32 = (outf != nullptr) && (fl != 0);
    if (!as_f32) {
        // scatter full 256x128 bf16 image (64 KB)
        #pragma unroll
        for (int i = 0; i < 4; ++i)
            #pragma unroll
            for (int j = 0; j < 4; ++j)
                #pragma unroll
                for (int r = 0; r < 4; ++r) {
                    int row = wr * 64 + i * 16 + quad * 4 + r;
                    int col = wc * 64 + j * 16 + l16;
                    int ch = col >> 3, off = col & 7;
                    smem[row * 128 + (((ch ^ (row & 7)) << 3) | off)] = f2b(acc[i][j][r]);
                }
        __syncthreads();
        if (mode == 1) {
            #pragma unroll
            for (int it = 0; it < 8; ++it) {
                int row = it * 32 + (tid >> 4);   // [0,256)
                int ch  = tid & 15;
                int t = (int)((bm + row) & 2047);
                bf16x8 v = *(const bf16x8*)(smem + row * 128 + ((ch ^ (row & 7)) << 3));
                bf16x8 p = *(const bf16x8*)(smem + row * 128 + (((ch ^ 8) ^ (row & 7)) << 3));
                const float* cr = rtab + t * 128 + (ch & 7) * 8;
                float sgn = (ch < 8) ? -1.f : 1.f;
                union { ushort_t u[8]; float4 f[1]; } o;
                #pragma unroll
                for (int j = 0; j < 8; ++j) {
                    float cv = cr[j], sv = cr[64 + j];
                    o.u[j] = f2b(b2f(((const ushort_t*)&v)[j]) * cv +
                                 sgn * b2f(((const ushort_t*)&p)[j]) * sv);
                }
                *(bf16x8*)(C + (bm + row) * Ndim + bn + ch * 8) = *(const bf16x8*)o.u;
            }
        } else {
            #pragma unroll
            for (int it = 0; it < 8; ++it) {
                int row = it * 32 + (tid >> 4);
                int ch  = tid & 15;
                bf16x8 v = *(const bf16x8*)(smem + row * 128 + ((ch ^ (row & 7)) << 3));
                *(bf16x8*)(C + (bm + row) * Ndim + bn + ch * 8) = v;
            }
        }
    } else {
        // fp32 epilogue: two 128-row halves through 64 KB LDS
        float* Fs = (float*)smem;
        #pragma unroll
        for (int half = 0; half < 2; ++half) {
            __syncthreads();
            if ((wr >> 1) == half) {
                #pragma unroll
                for (int i = 0; i < 4; ++i)
                    #pragma unroll
                    for (int j = 0; j < 4; ++j)
                        #pragma unroll
                        for (int r = 0; r < 4; ++r) {
                            int lrow = (wr & 1) * 64 + i * 16 + quad * 4 + r;  // [0,128)
                            int col = wc * 64 + j * 16 + l16;
                            int ch = col >> 2, off = col & 3;
                            Fs[lrow * 128 + (((ch ^ (lrow & 7)) << 2) | off)] = acc[i][j][r];
                        }
            }
            __syncthreads();
            #pragma unroll
            for (int it = 0; it < 8; ++it) {
                int lrow = it * 16 + (tid >> 5);   // [0,128)
                int ch = tid & 31;
                float4 v = *(const float4*)(Fs + lrow * 128 + ((ch ^ (lrow & 7)) << 2));
                *(float4*)(outf + (bm + half * 128 + lrow) * Ndim + bn + ch * 4) = v;
            }
        }
    }
}

// R7: fused QKV projection — ONE 768-block launch of the proven R6 body.
// Grid (16, 48): wsel = blockIdx.y >> 4 selects {Q,K,V}; dispatch order is
// wsel-sequential (blocks 0-255 all Q, then K, then V), 1 block/CU, and the
// per-256-group XCD swizzle is IDENTICAL to the solo launches -> co-resident
// working set per XCD matches a solo launch except at two group boundaries
// (unlike R1's interleaved 2/CU fusion that blew L2, FETCH 40->156 MB).
// Saves 2 launch gaps + 2 one-block-per-CU ramp tails, and surfaces GEMM
// counters as the #1 dispatch row for the next diagnostic round.
__global__ __launch_bounds__(512) void gemm_qkv3(const ushort_t* __restrict__ A,
                                                 const ushort_t* __restrict__ Wq,
                                                 const ushort_t* __restrict__ Wk,
                                                 const ushort_t* __restrict__ Wv,
                                                 ushort_t* __restrict__ Qo,
                                                 ushort_t* __restrict__ Ko,
                                                 ushort_t* __restrict__ Vto,
                                                 const float* __restrict__ rtab) {
    __shared__ ushort_t smem[4 * PBUF3];   // 96 KB
    const int wsel = blockIdx.y >> 4;      // 0:Q 1:K 2:V
    const int ym   = blockIdx.y & 15;
    const ushort_t* W = (wsel == 0) ? Wq : (wsel == 1) ? Wk : Wv;
    ushort_t* C       = (wsel == 0) ? Qo : (wsel == 1) ? Ko : Vto;
    const int mode = (wsel == 2) ? 2 : 1;
    // same per-group swizzle as solo launch
    const int wg  = ym * 16 + blockIdx.x;
    const int swz = (wg & 7) * 32 + (wg >> 3);
    const long bm = (long)(swz >> 4) * 256;
    const long bn = (long)(swz & 15) * 128;
    gemm3_body(A, W, C, nullptr, 0, rtab, mode, D_MODEL, bm, bn, smem);
}

// Final output projection (may need fp32 epilogue).
__global__ __launch_bounds__(512) void gemm_nt3(const ushort_t* __restrict__ A,
                                                const ushort_t* __restrict__ W,
                                                ushort_t* __restrict__ C,
                                                float* __restrict__ outf,
                                                const int* __restrict__ flag,
                                                const float* __restrict__ rtab,
                                                int mode, int Ndim) {
    __shared__ ushort_t smem[4 * PBUF3];   // 96 KB
    const int wg  = blockIdx.y * 16 + blockIdx.x;
    const int swz = (wg & 7) * 32 + (wg >> 3);
    const long bm = (long)(swz >> 4) * 256;
    const long bn = (long)(swz & 15) * 128;
    // Retire the flag read before the pipeline so vmcnt counting is exact.
    int fl = flag ? *flag : 0;
    asm volatile("" :: "v"(fl));
    asm volatile("s_waitcnt vmcnt(0)" ::: "memory");
    gemm3_body(A, W, C, outf, fl, rtab, mode, Ndim, bm, bn, smem);
}

// ---------------------------------------------------------------------------
// Causal flash attention — R3 structure + R6 CU-draw balancing (84.9 us).
// Blocks round-robin to CUs as {c, c+256, c+512, c+768}; remap g=bx>>5 -> qb
// so each CU draw sums to a constant 62 iters (was 52..80 -> ~20% tail):
//   g in [0,8): 31-g | [8,16): g-8 | [16,24): 39-g | [24,32): g-16
// R4 lesson kept: 1024 blocks, 4/CU, 64 VGPR — do not trade TLP for
// per-block work.
// ---------------------------------------------------------------------------
#define NQT (T_SEQ / 64)
#define C2SM 0.1275174452f   // 128^-0.5 * log2(e)
#define MFIX 96.0f

__global__ __launch_bounds__(256, 4) void attn_kernel(const ushort_t* __restrict__ Q,
                                                      const ushort_t* __restrict__ K,
                                                      const ushort_t* __restrict__ Vt,
                                                      ushort_t* __restrict__ O) {
    __shared__ ushort_t Ks[64 * 128];
    __shared__ ushort_t Vs[128 * 64];
    __shared__ ushort_t Ps[4 * 16 * 64];

    const int tid = threadIdx.x;
    const int lane = tid & 63, w = tid >> 6;
    const int quad = lane >> 4, l16 = lane & 15;
    const int bx = blockIdx.x;
    const int g = bx >> 5;
    int qb;
    if (g < 8)       qb = 31 - g;
    else if (g < 16) qb = g - 8;
    else if (g < 24) qb = 39 - g;
    else             qb = g - 16;
    const int bh = bx & 31;
    const int h = bh & 15, b = bh >> 4;

    const size_t qkbase = ((size_t)(b * T_SEQ)) * D_MODEL + h * HD;
    const size_t vtbase = ((size_t)((b * NH + h) * HD)) * T_SEQ;
    const int ck0 = w * 256 + lane;
    ushort_t* Pw = Ps + w * 1024;

    auto stage_K = [&](int kvb) {
        #pragma unroll
        for (int i = 0; i < 4; ++i) {
            int ck = ck0 + i * 64;
            int r = ck >> 4, gg = (ck & 15) ^ (r & 15);
            g2l16(K + qkbase + (size_t)(kvb * 64 + r) * D_MODEL + gg * 8,
                  (ushort_t*)Ks + (size_t)(w * 256 + i * 64) * 8);
        }
    };
    auto stage_V = [&](int kvb) {
        #pragma unroll
        for (int i = 0; i < 4; ++i) {
            int ck = ck0 + i * 64;
            int r = ck >> 3, gg = (ck & 7) ^ (r & 7);
            g2l16(Vt + vtbase + (size_t)r * T_SEQ + kvb * 64 + gg * 8,
                  (ushort_t*)Vs + (size_t)(w * 256 + i * 64) * 8);
        }
    };

    bf16x8 qf[4];
    {
        const ushort_t* qrow = Q + qkbase + (size_t)(qb * 64 + w * 16 + l16) * D_MODEL;
        #pragma unroll
        for (int ks = 0; ks < 4; ++ks)
            qf[ks] = *(const bf16x8*)(qrow + ks * 32 + quad * 8);
    }

    float l_i[4] = {0.f, 0.f, 0.f, 0.f};   // lane-partial; reduced at end
    f32x4 accO[8];
    for (int i = 0; i < 8; ++i) accO[i] = {0.f, 0.f, 0.f, 0.f};

    stage_K(0);                              // prologue

    for (int kvb = 0; kvb <= qb; ++kvb) {
        __syncthreads();                     // K(kvb) landed; Vs free
        stage_V(kvb);                        // in flight during QK^T+softmax

        f32x4 accS[4];
        for (int i = 0; i < 4; ++i) accS[i] = {0.f, 0.f, 0.f, 0.f};
        __builtin_amdgcn_s_setprio(1);
        #pragma unroll
        for (int ks = 0; ks < 4; ++ks) {
            #pragma unroll
            for (int ct = 0; ct < 4; ++ct) {
                bf16x8 bb = *(const bf16x8*)(Ks + (ct * 16 + l16) * 128 +
                                             (((ks * 4 + quad) ^ l16) * 8));
                accS[ct] = __builtin_amdgcn_mfma_f32_16x16x32_bf16(qf[ks], bb, accS[ct], 0, 0, 0);
            }
        }
        __builtin_amdgcn_s_setprio(0);

        if (kvb == qb) {   // diagonal: causal mask
            int qloc = w * 16 + quad * 4;
            for (int ct = 0; ct < 4; ++ct) {
                int key = ct * 16 + l16;
                for (int r = 0; r < 4; ++r)
                    if (key > qloc + r) accS[ct][r] = -1e30f;
            }
        }

        // p = exp2((s - M) * c); accumulate lane-partial l; store P to LDS
        #pragma unroll
        for (int ct = 0; ct < 4; ++ct) {
            #pragma unroll
            for (int r = 0; r < 4; ++r) {
                float pv = exp2f((accS[ct][r] - MFIX) * C2SM);
                l_i[r] += pv;
                int col = ct * 16 + l16;
                int row = quad * 4 + r;
                Pw[row * 64 + ((((col >> 3) ^ (row & 7)) << 3) | (col & 7))] = f2b(pv);
            }
        }

        __syncthreads();                     // V(kvb) landed; Ks free
        if (kvb < qb) stage_K(kvb + 1);      // in flight during PV

        __builtin_amdgcn_s_setprio(1);
        #pragma unroll
        for (int kk2 = 0; kk2 < 2; ++kk2) {
            bf16x8 a = *(const bf16x8*)(Pw + l16 * 64 + (((kk2 * 4 + quad) ^ (l16 & 7)) << 3));
            #pragma unroll
            for (int ct = 0; ct < 8; ++ct) {
                bf16x8 bb = *(const bf16x8*)(Vs + (ct * 16 + l16) * 64 +
                                             (((kk2 * 4 + quad) ^ (l16 & 7)) * 8));
                accO[ct] = __builtin_amdgcn_mfma_f32_16x16x32_bf16(a, bb, accO[ct], 0, 0, 0);
            }
        }
        __builtin_amdgcn_s_setprio(0);
    }

    // end-of-loop l reduction across the 16 lanes of each quad group
    #pragma unroll
    for (int r = 0; r < 4; ++r) {
        for (int off = 1; off < 16; off <<= 1)
            l_i[r] += __shfl_xor(l_i[r], off);
        l_i[r] = 1.f / l_i[r];
    }

    for (int ct = 0; ct < 8; ++ct)
        for (int r = 0; r < 4; ++r) {
            size_t row = (size_t)(b * T_SEQ + qb * 64 + w * 16 + quad * 4 + r);
            O[row * D_MODEL + h * HD + ct * 16 + l16] = f2b(accO[ct][r] * l_i[r]);
        }
}

// ---------------------------------------------------------------------------
extern "C" void kernel_launch(void* const* d_in, const int* in_sizes, int n_in,
                              void* d_out, int out_size, void* d_ws, size_t ws_size,
                              hipStream_t stream) {
    const size_t TEN = (size_t)M_ROWS * D_MODEL;
    const size_t WEL = (size_t)D_MODEL * D_MODEL;

    char* ws = (char*)d_ws;
    int* flag = (int*)ws;
    ushort_t* xb  = (ushort_t*)(ws + 256);
    ushort_t* Wqb = xb  + TEN;
    ushort_t* Wkb = Wqb + WEL;
    ushort_t* Wvb = Wkb + WEL;
    ushort_t* Wob = Wvb + WEL;
    ushort_t* Qb  = Wob + WEL;
    ushort_t* Kb  = Qb + TEN;
    ushort_t* attn = Kb + TEN;
    ushort_t* Vt  = attn + TEN;
    float* rtab = (float*)(Vt + TEN); // 2048*128 floats = 1 MB

    detect_dtype<<<1, 256, 0, stream>>>((const ushort_t*)d_in[0], flag);
    rope_table<<<(T_SEQ * 64) / 256, 256, 0, stream>>>(rtab);
    convert_all<<<(int)((TEN + 4 * WEL) / 8 / 256), 256, 0, stream>>>(
        d_in[0], d_in[1], d_in[2], d_in[3], d_in[4], xb, flag);

    // Fused QKV: one 768-block launch (wsel-sequential dispatch, 1/CU).
    gemm_qkv3<<<dim3(16, 48), 512, 0, stream>>>(xb, Wqb, Wkb, Wvb, Qb, Kb, Vt, rtab);

    attn_kernel<<<dim3(NQT * NB * NH), 256, 0, stream>>>(Qb, Kb, Vt, attn);

    gemm_nt3<<<dim3(16, 16), 512, 0, stream>>>(attn, Wob, (ushort_t*)d_out,
                                               (float*)d_out, flag, rtab, 0, D_MODEL);
}

// Round 9
// 366.770 us; speedup vs baseline: 1.1422x; 1.0068x over previous
//
#include <hip/hip_runtime.h>

typedef unsigned short ushort_t;
typedef short bf16x8 __attribute__((ext_vector_type(8)));
typedef float f32x4 __attribute__((ext_vector_type(4)));

#define D_MODEL 2048
#define T_SEQ 2048
#define NB 2
#define NH 16
#define HD 128
#define M_ROWS 4096

__device__ __forceinline__ float b2f(unsigned short u) {
    return __uint_as_float(((unsigned)u) << 16);
}
__device__ __forceinline__ unsigned short f2b(float f) {
    unsigned u = __float_as_uint(f);
    u += 0x7fffu + ((u >> 16) & 1u);
    return (unsigned short)(u >> 16);
}

// async global->LDS, 16B per lane. lds base must be wave-uniform.
__device__ __forceinline__ void g2l16(const ushort_t* g, ushort_t* l) {
    __builtin_amdgcn_global_load_lds(
        (const __attribute__((address_space(1))) unsigned int*)g,
        (__attribute__((address_space(3))) unsigned int*)l, 16, 0, 0);
}

// ---------------------------------------------------------------------------
// Input dtype probe (1 = fp32 inputs). FALLBACK ONLY: host decides dtype from
// in_sizes[0] (fp32 = TEN*4 bytes, bf16 = TEN*2); this kernel launches only
// if in_sizes uses an unexpected convention.
// ---------------------------------------------------------------------------
__global__ void detect_dtype(const ushort_t* __restrict__ x, int* __restrict__ flag) {
    __shared__ int cnt;
    if (threadIdx.x == 0) cnt = 0;
    __syncthreads();
    int c = 0;
    for (int i = threadIdx.x; i < 8192; i += 256) {
        int e = (x[i] >> 7) & 0xFF;
        if (e >= 0xC8) ++c;
    }
    atomicAdd(&cnt, c);
    __syncthreads();
    if (threadIdx.x == 0) *flag = (cnt > 16) ? 1 : 0;
}

// ---------------------------------------------------------------------------
// R8: one fused elementwise pass = {x,Wq,Wk,Wv,Wo} conversion + RoPE table.
// Blocks [0, 12288): convert 2048 elems each (dsts contiguous in workspace).
// Blocks [12288, 12800): RoPE cos/sin table (identical math to old kernel).
// hostfl >= 0: dtype known on host (no flag deref); -1: read *flag.
// ---------------------------------------------------------------------------
#define NCONVB 12288   // (TEN + 4*WEL) / 2048
#define NROPEB 512     // (T_SEQ * 64) / 256

__global__ void convert_rope(const void* __restrict__ s0, const void* __restrict__ s1,
                             const void* __restrict__ s2, const void* __restrict__ s3,
                             const void* __restrict__ s4, ushort_t* __restrict__ dst,
                             float* __restrict__ rtab,
                             int hostfl, const int* __restrict__ flag) {
    const int bx = blockIdx.x;
    if (bx >= NCONVB) {
        int tid = (bx - NCONVB) * 256 + threadIdx.x;   // t*64 + i
        int i = tid & 63, t = tid >> 6;
        float ang = (float)t * exp2f(-(float)i * 0.20762050593046015f);
        rtab[t * 128 + i]      = cosf(ang);
        rtab[t * 128 + 64 + i] = sinf(ang);
        return;
    }
    const size_t TENc = (size_t)M_ROWS * D_MODEL;   // 2^23
    const size_t WELc = (size_t)D_MODEL * D_MODEL;  // 2^22
    size_t i = ((size_t)bx * 256 + threadIdx.x) * 8;
    const void* src;
    size_t off;
    if (i < TENc) {
        src = s0; off = i;
    } else {
        size_t j = i - TENc;
        int wsel = (int)(j >> 22);
        src = (wsel == 0) ? s1 : (wsel == 1) ? s2 : (wsel == 2) ? s3 : s4;
        off = j & (WELc - 1);
    }
    const int fl = (hostfl >= 0) ? hostfl : *flag;
    if (fl) {
        const float* s = (const float*)src + off;
        union { ushort_t u[8]; float4 f; } pk;
        #pragma unroll
        for (int j2 = 0; j2 < 8; ++j2) pk.u[j2] = f2b(s[j2]);
        *(float4*)(dst + i) = pk.f;
    } else {
        *(float4*)(dst + i) = *(const float4*)((const ushort_t*)src + off);
    }
}

// ---------------------------------------------------------------------------
// R6 GEMM body: 256x128 tile, 512 threads (8 waves, 4Mx2N, per-wave 64x64),
// fine-interleaved counted-vmcnt pipeline, BK=32, 4 LDS buffers.
// R7 counters: 909 TF, MfmaUtil 38.9%, ~0 conflicts, HBM 14% — known-good.
// Next GEMM lever (not this round): per-wave 128x64 reuse geometry
// (LDS-read-bound: ~256cy LDS vs ~155cy MFMA per K-step at 64x64/wave).
// mode 0: bf16 store (or fp32 if outf && fl); 1: fused RoPE; 2: Vt.
// ---------------------------------------------------------------------------
#define ABUF3 (256 * 32)          // 8192 elems
#define WBUF3 (128 * 32)          // 4096 elems
#define PBUF3 (ABUF3 + WBUF3)     // 12288 elems = 24 KB per buffer

__device__ __forceinline__ void gemm3_body(const ushort_t* __restrict__ A,
                                           const ushort_t* __restrict__ W,
                                           ushort_t* __restrict__ C,
                                           float* __restrict__ outf,
                                           int fl,
                                           const float* __restrict__ rtab,
                                           int mode, int Ndim,
                                           long bm, long bn,
                                           ushort_t* smem) {
    const int tid  = threadIdx.x;
    const int lane = tid & 63;
    const int w    = tid >> 6;             // 0..7
    const int wr   = w >> 1;               // 0..3 : 64-row group
    const int wc   = w & 1;                // 0..1 : 64-col group
    const int quad = lane >> 4, l16 = lane & 15;
    const int Kd   = D_MODEL;

    f32x4 acc[4][4];
    #pragma unroll
    for (int i = 0; i < 4; ++i)
        #pragma unroll
        for (int j = 0; j < 4; ++j) acc[i][j] = {0.f, 0.f, 0.f, 0.f};

    // staging thread mapping: per K-step (32 elems) each thread does
    // 2 A-loads + 1 W-load of 16B. Wave-instruction j covers 16 rows (1KB).
    const int lr = lane >> 2;              // row within 16-row group
    const int cl = lane & 3;               // 16B chunk within 64B row
    const int rowA0 = (w * 2 + 0) * 16 + lr;
    const int rowA1 = (w * 2 + 1) * 16 + lr;
    const int rowW  = w * 16 + lr;
    // pre-swizzled global sources: LDS slot cl holds global chunk cl^f(row)
    const ushort_t* gA0 = A + (bm + rowA0) * Kd + ((cl ^ ((rowA0 >> 1) & 3)) * 8);
    const ushort_t* gA1 = A + (bm + rowA1) * Kd + ((cl ^ ((rowA1 >> 1) & 3)) * 8);
    const ushort_t* gW  = W + (bn + rowW)  * Kd + ((cl ^ ((rowW  >> 1) & 3)) * 8);

    const int fsl = (l16 >> 1) & 3;        // read-side swizzle

    auto stage = [&](int s) {
        ushort_t* As = smem + (s & 3) * PBUF3;
        ushort_t* Ws = As + ABUF3;
        const int ko = s * 32;
        g2l16(gA0 + ko, As + (w * 2 + 0) * 512);
        g2l16(gA1 + ko, As + (w * 2 + 1) * 512);
        g2l16(gW + ko, Ws + w * 512);
    };

    auto kstep = [&](int s, int vm, bool do_stage) {
        if (vm == 6)      asm volatile("s_waitcnt vmcnt(6)" ::: "memory");
        else if (vm == 3) asm volatile("s_waitcnt vmcnt(3)" ::: "memory");
        else              asm volatile("s_waitcnt vmcnt(0)" ::: "memory");
        __builtin_amdgcn_sched_barrier(0);
        __builtin_amdgcn_s_barrier();
        __builtin_amdgcn_sched_barrier(0);
        if (do_stage) stage(s + 3);
        const ushort_t* As = smem + (s & 3) * PBUF3;
        const ushort_t* Ws = As + ABUF3;
        bf16x8 af[4], bf[4];
        #pragma unroll
        for (int i = 0; i < 4; ++i)
            af[i] = *(const bf16x8*)(As + (wr * 64 + i * 16 + l16) * 32 + (quad ^ fsl) * 8);
        #pragma unroll
        for (int j = 0; j < 4; ++j)
            bf[j] = *(const bf16x8*)(Ws + (wc * 64 + j * 16 + l16) * 32 + (quad ^ fsl) * 8);
        __builtin_amdgcn_s_setprio(1);
        #pragma unroll
        for (int i = 0; i < 4; ++i)
            #pragma unroll
            for (int j = 0; j < 4; ++j)
                acc[i][j] = __builtin_amdgcn_mfma_f32_16x16x32_bf16(af[i], bf[j], acc[i][j], 0, 0, 0);
        __builtin_amdgcn_s_setprio(0);
    };

    stage(0); stage(1); stage(2);          // 9 loads in flight
    #pragma unroll 4
    for (int s = 0; s < 60; ++s) kstep(s, 6, true);   // stages up to 62
    kstep(60, 6, true);                    // stages 63
    kstep(61, 6, false);
    kstep(62, 3, false);
    kstep(63, 0, false);
    __syncthreads();   // all LDS reads retired before epilogue reuses smem

    if (mode == 2) {
        // Vt epilogue: transposed image [128 d][256 t] in LDS, store along t.
        #pragma unroll
        for (int i = 0; i < 4; ++i)
            #pragma unroll
            for (int j = 0; j < 4; ++j)
                #pragma unroll
                for (int r = 0; r < 4; ++r) {
                    int row = wr * 64 + i * 16 + quad * 4 + r;   // t in tile [0,256)
                    int col = wc * 64 + j * 16 + l16;            // d in head [0,128)
                    smem[col * 256 + ((((row >> 3) ^ (col & 7)) << 3) | (row & 7))] =
                        f2b(acc[i][j][r]);
                }
        __syncthreads();
        const int b = (int)(bm >> 11), t0 = (int)(bm & 2047), h = (int)(bn >> 7);
        const size_t obase = ((size_t)(b * NH + h) * HD) * T_SEQ;
        #pragma unroll
        for (int it = 0; it < 8; ++it) {
            int dd  = it * 16 + (tid >> 5);     // [0,128)
            int tch = tid & 31;                 // [0,32): 256 t / 8
            bf16x8 v = *(const bf16x8*)(smem + dd * 256 + ((tch ^ (dd & 7)) << 3));
            *(bf16x8*)(C + obase + (size_t)dd * T_SEQ + t0 + tch * 8) = v;
        }
        return;
    }

    const int as_f32 = (outf != nullptr) && (fl != 0);
    if (!as_f32) {
        // scatter full 256x128 bf16 image (64 KB)
        #pragma unroll
        for (int i = 0; i < 4; ++i)
            #pragma unroll
            for (int j = 0; j < 4; ++j)
                #pragma unroll
                for (int r = 0; r < 4; ++r) {
                    int row = wr * 64 + i * 16 + quad * 4 + r;
                    int col = wc * 64 + j * 16 + l16;
                    int ch = col >> 3, off = col & 7;
                    smem[row * 128 + (((ch ^ (row & 7)) << 3) | off)] = f2b(acc[i][j][r]);
                }
        __syncthreads();
        if (mode == 1) {
            #pragma unroll
            for (int it = 0; it < 8; ++it) {
                int row = it * 32 + (tid >> 4);   // [0,256)
                int ch  = tid & 15;
                int t = (int)((bm + row) & 2047);
                bf16x8 v = *(const bf16x8*)(smem + row * 128 + ((ch ^ (row & 7)) << 3));
                bf16x8 p = *(const bf16x8*)(smem + row * 128 + (((ch ^ 8) ^ (row & 7)) << 3));
                const float* cr = rtab + t * 128 + (ch & 7) * 8;
                float sgn = (ch < 8) ? -1.f : 1.f;
                union { ushort_t u[8]; float4 f[1]; } o;
                #pragma unroll
                for (int j = 0; j < 8; ++j) {
                    float cv = cr[j], sv = cr[64 + j];
                    o.u[j] = f2b(b2f(((const ushort_t*)&v)[j]) * cv +
                                 sgn * b2f(((const ushort_t*)&p)[j]) * sv);
                }
                *(bf16x8*)(C + (bm + row) * Ndim + bn + ch * 8) = *(const bf16x8*)o.u;
            }
        } else {
            #pragma unroll
            for (int it = 0; it < 8; ++it) {
                int row = it * 32 + (tid >> 4);
                int ch  = tid & 15;
                bf16x8 v = *(const bf16x8*)(smem + row * 128 + ((ch ^ (row & 7)) << 3));
                *(bf16x8*)(C + (bm + row) * Ndim + bn + ch * 8) = v;
            }
        }
    } else {
        // fp32 epilogue: two 128-row halves through 64 KB LDS
        float* Fs = (float*)smem;
        #pragma unroll
        for (int half = 0; half < 2; ++half) {
            __syncthreads();
            if ((wr >> 1) == half) {
                #pragma unroll
                for (int i = 0; i < 4; ++i)
                    #pragma unroll
                    for (int j = 0; j < 4; ++j)
                        #pragma unroll
                        for (int r = 0; r < 4; ++r) {
                            int lrow = (wr & 1) * 64 + i * 16 + quad * 4 + r;  // [0,128)
                            int col = wc * 64 + j * 16 + l16;
                            int ch = col >> 2, off = col & 3;
                            Fs[lrow * 128 + (((ch ^ (lrow & 7)) << 2) | off)] = acc[i][j][r];
                        }
            }
            __syncthreads();
            #pragma unroll
            for (int it = 0; it < 8; ++it) {
                int lrow = it * 16 + (tid >> 5);   // [0,128)
                int ch = tid & 31;
                float4 v = *(const float4*)(Fs + lrow * 128 + ((ch ^ (lrow & 7)) << 2));
                *(float4*)(outf + (bm + half * 128 + lrow) * Ndim + bn + ch * 4) = v;
            }
        }
    }
}

// Fused QKV projection — ONE 768-block launch (R7: 909 TF, known-good).
__global__ __launch_bounds__(512) void gemm_qkv3(const ushort_t* __restrict__ A,
                                                 const ushort_t* __restrict__ Wq,
                                                 const ushort_t* __restrict__ Wk,
                                                 const ushort_t* __restrict__ Wv,
                                                 ushort_t* __restrict__ Qo,
                                                 ushort_t* __restrict__ Ko,
                                                 ushort_t* __restrict__ Vto,
                                                 const float* __restrict__ rtab) {
    __shared__ ushort_t smem[4 * PBUF3];   // 96 KB
    const int wsel = blockIdx.y >> 4;      // 0:Q 1:K 2:V
    const int ym   = blockIdx.y & 15;
    const ushort_t* W = (wsel == 0) ? Wq : (wsel == 1) ? Wk : Wv;
    ushort_t* C       = (wsel == 0) ? Qo : (wsel == 1) ? Ko : Vto;
    const int mode = (wsel == 2) ? 2 : 1;
    // same per-group swizzle as solo launch
    const int wg  = ym * 16 + blockIdx.x;
    const int swz = (wg & 7) * 32 + (wg >> 3);
    const long bm = (long)(swz >> 4) * 256;
    const long bn = (long)(swz & 15) * 128;
    gemm3_body(A, W, C, nullptr, 0, rtab, mode, D_MODEL, bm, bn, smem);
}

// Final output projection (may need fp32 epilogue). hostfl >= 0: host-known
// dtype; -1: read *flag (fallback path).
__global__ __launch_bounds__(512) void gemm_nt3(const ushort_t* __restrict__ A,
                                                const ushort_t* __restrict__ W,
                                                ushort_t* __restrict__ C,
                                                float* __restrict__ outf,
                                                int hostfl,
                                                const int* __restrict__ flag,
                                                const float* __restrict__ rtab,
                                                int mode, int Ndim) {
    __shared__ ushort_t smem[4 * PBUF3];   // 96 KB
    const int wg  = blockIdx.y * 16 + blockIdx.x;
    const int swz = (wg & 7) * 32 + (wg >> 3);
    const long bm = (long)(swz >> 4) * 256;
    const long bn = (long)(swz & 15) * 128;
    // Resolve fl and retire any flag read before the pipeline so the loop's
    // vmcnt counting stays exact.
    int fl = (hostfl >= 0) ? hostfl : *flag;
    asm volatile("" :: "v"(fl));
    asm volatile("s_waitcnt vmcnt(0)" ::: "memory");
    gemm3_body(A, W, C, outf, fl, rtab, mode, Ndim, bm, bn, smem);
}

// ---------------------------------------------------------------------------
// Causal flash attention — R3 structure + R6 CU-draw balancing (84.9 us).
// Blocks round-robin to CUs as {c, c+256, c+512, c+768}; remap g=bx>>5 -> qb
// so each CU draw sums to a constant 62 iters:
//   g in [0,8): 31-g | [8,16): g-8 | [16,24): 39-g | [24,32): g-16
// R4 lesson kept: 1024 blocks, 4/CU, 64 VGPR — do not trade TLP for
// per-block work.
// ---------------------------------------------------------------------------
#define NQT (T_SEQ / 64)
#define C2SM 0.1275174452f   // 128^-0.5 * log2(e)
#define MFIX 96.0f

__global__ __launch_bounds__(256, 4) void attn_kernel(const ushort_t* __restrict__ Q,
                                                      const ushort_t* __restrict__ K,
                                                      const ushort_t* __restrict__ Vt,
                                                      ushort_t* __restrict__ O) {
    __shared__ ushort_t Ks[64 * 128];
    __shared__ ushort_t Vs[128 * 64];
    __shared__ ushort_t Ps[4 * 16 * 64];

    const int tid = threadIdx.x;
    const int lane = tid & 63, w = tid >> 6;
    const int quad = lane >> 4, l16 = lane & 15;
    const int bx = blockIdx.x;
    const int g = bx >> 5;
    int qb;
    if (g < 8)       qb = 31 - g;
    else if (g < 16) qb = g - 8;
    else if (g < 24) qb = 39 - g;
    else             qb = g - 16;
    const int bh = bx & 31;
    const int h = bh & 15, b = bh >> 4;

    const size_t qkbase = ((size_t)(b * T_SEQ)) * D_MODEL + h * HD;
    const size_t vtbase = ((size_t)((b * NH + h) * HD)) * T_SEQ;
    const int ck0 = w * 256 + lane;
    ushort_t* Pw = Ps + w * 1024;

    auto stage_K = [&](int kvb) {
        #pragma unroll
        for (int i = 0; i < 4; ++i) {
            int ck = ck0 + i * 64;
            int r = ck >> 4, gg = (ck & 15) ^ (r & 15);
            g2l16(K + qkbase + (size_t)(kvb * 64 + r) * D_MODEL + gg * 8,
                  (ushort_t*)Ks + (size_t)(w * 256 + i * 64) * 8);
        }
    };
    auto stage_V = [&](int kvb) {
        #pragma unroll
        for (int i = 0; i < 4; ++i) {
            int ck = ck0 + i * 64;
            int r = ck >> 3, gg = (ck & 7) ^ (r & 7);
            g2l16(Vt + vtbase + (size_t)r * T_SEQ + kvb * 64 + gg * 8,
                  (ushort_t*)Vs + (size_t)(w * 256 + i * 64) * 8);
        }
    };

    bf16x8 qf[4];
    {
        const ushort_t* qrow = Q + qkbase + (size_t)(qb * 64 + w * 16 + l16) * D_MODEL;
        #pragma unroll
        for (int ks = 0; ks < 4; ++ks)
            qf[ks] = *(const bf16x8*)(qrow + ks * 32 + quad * 8);
    }

    float l_i[4] = {0.f, 0.f, 0.f, 0.f};   // lane-partial; reduced at end
    f32x4 accO[8];
    for (int i = 0; i < 8; ++i) accO[i] = {0.f, 0.f, 0.f, 0.f};

    stage_K(0);                              // prologue

    for (int kvb = 0; kvb <= qb; ++kvb) {
        __syncthreads();                     // K(kvb) landed; Vs free
        stage_V(kvb);                        // in flight during QK^T+softmax

        f32x4 accS[4];
        for (int i = 0; i < 4; ++i) accS[i] = {0.f, 0.f, 0.f, 0.f};
        __builtin_amdgcn_s_setprio(1);
        #pragma unroll
        for (int ks = 0; ks < 4; ++ks) {
            #pragma unroll
            for (int ct = 0; ct < 4; ++ct) {
                bf16x8 bb = *(const bf16x8*)(Ks + (ct * 16 + l16) * 128 +
                                             (((ks * 4 + quad) ^ l16) * 8));
                accS[ct] = __builtin_amdgcn_mfma_f32_16x16x32_bf16(qf[ks], bb, accS[ct], 0, 0, 0);
            }
        }
        __builtin_amdgcn_s_setprio(0);

        if (kvb == qb) {   // diagonal: causal mask
            int qloc = w * 16 + quad * 4;
            for (int ct = 0; ct < 4; ++ct) {
                int key = ct * 16 + l16;
                for (int r = 0; r < 4; ++r)
                    if (key > qloc + r) accS[ct][r] = -1e30f;
            }
        }

        // p = exp2((s - M) * c); accumulate lane-partial l; store P to LDS
        #pragma unroll
        for (int ct = 0; ct < 4; ++ct) {
            #pragma unroll
            for (int r = 0; r < 4; ++r) {
                float pv = exp2f((accS[ct][r] - MFIX) * C2SM);
                l_i[r] += pv;
                int col = ct * 16 + l16;
                int row = quad * 4 + r;
                Pw[row * 64 + ((((col >> 3) ^ (row & 7)) << 3) | (col & 7))] = f2b(pv);
            }
        }

        __syncthreads();                     // V(kvb) landed; Ks free
        if (kvb < qb) stage_K(kvb + 1);      // in flight during PV

        __builtin_amdgcn_s_setprio(1);
        #pragma unroll
        for (int kk2 = 0; kk2 < 2; ++kk2) {
            bf16x8 a = *(const bf16x8*)(Pw + l16 * 64 + (((kk2 * 4 + quad) ^ (l16 & 7)) << 3));
            #pragma unroll
            for (int ct = 0; ct < 8; ++ct) {
                bf16x8 bb = *(const bf16x8*)(Vs + (ct * 16 + l16) * 64 +
                                             (((kk2 * 4 + quad) ^ (l16 & 7)) * 8));
                accO[ct] = __builtin_amdgcn_mfma_f32_16x16x32_bf16(a, bb, accO[ct], 0, 0, 0);
            }
        }
        __builtin_amdgcn_s_setprio(0);
    }

    // end-of-loop l reduction across the 16 lanes of each quad group
    #pragma unroll
    for (int r = 0; r < 4; ++r) {
        for (int off = 1; off < 16; off <<= 1)
            l_i[r] += __shfl_xor(l_i[r], off);
        l_i[r] = 1.f / l_i[r];
    }

    for (int ct = 0; ct < 8; ++ct)
        for (int r = 0; r < 4; ++r) {
            size_t row = (size_t)(b * T_SEQ + qb * 64 + w * 16 + quad * 4 + r);
            O[row * D_MODEL + h * HD + ct * 16 + l16] = f2b(accO[ct][r] * l_i[r]);
        }
}

// ---------------------------------------------------------------------------
extern "C" void kernel_launch(void* const* d_in, const int* in_sizes, int n_in,
                              void* d_out, int out_size, void* d_ws, size_t ws_size,
                              hipStream_t stream) {
    const size_t TEN = (size_t)M_ROWS * D_MODEL;
    const size_t WEL = (size_t)D_MODEL * D_MODEL;

    char* ws = (char*)d_ws;
    int* flag = (int*)ws;
    ushort_t* xb  = (ushort_t*)(ws + 256);
    ushort_t* Wqb = xb  + TEN;
    ushort_t* Wkb = Wqb + WEL;
    ushort_t* Wvb = Wkb + WEL;
    ushort_t* Wob = Wvb + WEL;
    ushort_t* Qb  = Wob + WEL;
    ushort_t* Kb  = Qb + TEN;
    ushort_t* attn = Kb + TEN;
    ushort_t* Vt  = attn + TEN;
    float* rtab = (float*)(Vt + TEN); // 2048*128 floats = 1 MB

    // Host-side dtype decision from in_sizes[0] (bytes). Fallback to the GPU
    // probe only if the convention is unexpected.
    int hostfl = -1;
    if (in_sizes && n_in > 0) {
        if (in_sizes[0] == (int)(TEN * 4)) hostfl = 1;        // fp32
        else if (in_sizes[0] == (int)(TEN * 2)) hostfl = 0;   // bf16
    }
    if (hostfl < 0)
        detect_dtype<<<1, 256, 0, stream>>>((const ushort_t*)d_in[0], flag);

    convert_rope<<<NCONVB + NROPEB, 256, 0, stream>>>(
        d_in[0], d_in[1], d_in[2], d_in[3], d_in[4], xb, rtab, hostfl, flag);

    // Fused QKV: one 768-block launch (wsel-sequential dispatch, 1/CU).
    gemm_qkv3<<<dim3(16, 48), 512, 0, stream>>>(xb, Wqb, Wkb, Wvb, Qb, Kb, Vt, rtab);

    attn_kernel<<<dim3(NQT * NB * NH), 256, 0, stream>>>(Qb, Kb, Vt, attn);

    gemm_nt3<<<dim3(16, 16), 512, 0, stream>>>(attn, Wob, (ushort_t*)d_out,
                                               (float*)d_out, hostfl, flag, rtab,
                                               0, D_MODEL);
}